// Round 8
// baseline (1290.812 us; speedup 1.0000x reference)
//
#include <hip/hip_runtime.h>
#include <stdint.h>

// ---------------------------------------------------------------------------
// DeltaNet (gated delta rule) forward, MI355X gfx950. Round 8.
// Round 7: PASS 1043us; phaseA 406us = LDS-issue-bound (2 scalar ds_read per
// FMA; VALUBusy 24.7%). This round: register-blocked 4x4 tiles + float4 LDS
// reads for ALL matmul loops in phaseA/phaseB2/phaseC (fp32, sum order
// preserved -> absmax must stay exactly 0.04296875).
//   phaseA: stage kf+kT; G via kT-only; T-subst -> Tt (transposed); vf over
//           kT; W,M,Uv,N via float4 row reads; packed global stores.
//   phaseB2/phaseC: same blocking with transposed planes (WT, qT, PmT).
// P column map: [0,1024) q | [1024,3072) k | [3072,5120) v |
//   [5120,5152) beta-pre | [5152,5168) a-pre | [5168,6192) gate | pad
// ---------------------------------------------------------------------------

typedef unsigned short u16;
typedef __attribute__((ext_vector_type(8))) short bf16x8;
typedef __attribute__((ext_vector_type(4))) float f32x4;
typedef __attribute__((ext_vector_type(2))) float f32x2;
typedef __attribute__((ext_vector_type(4))) unsigned short u16x4;

#define TT 2048
#define NP 6208
#define NC 64
#define CS 64

__device__ __forceinline__ u16 f2bf(float f) {
  union { float f; uint32_t u; } v; v.f = f;
  uint32_t r = v.u + 0x7fffu + ((v.u >> 16) & 1u);  // RNE
  return (u16)(r >> 16);
}
__device__ __forceinline__ float bf2f(u16 b) {
  union { uint32_t u; float f; } v; v.u = ((uint32_t)b) << 16; return v.f;
}

__global__ void cvt_kernel(const float* __restrict__ src, u16* __restrict__ dst, long n) {
  long i = (long)blockIdx.x * 256 + threadIdx.x;
  if (i < n) dst[i] = f2bf(src[i]);
}

__global__ __launch_bounds__(256) void transT_kernel(const float* __restrict__ src,
    u16* __restrict__ dst, int rows, int cols) {
  __shared__ float tile[32][33];
  const int tx = threadIdx.x & 31, ty = threadIdx.x >> 5;
  const int c0 = blockIdx.x * 32, r0 = blockIdx.y * 32;
  for (int rr = ty; rr < 32; rr += 8)
    if (c0 + tx < cols) tile[rr][tx] = src[(size_t)(r0 + rr) * cols + c0 + tx];
  __syncthreads();
  for (int rr = ty; rr < 32; rr += 8)
    if (c0 + rr < cols) dst[(size_t)(c0 + rr) * rows + r0 + tx] = f2bf(tile[tx][rr]);
}

__global__ __launch_bounds__(256) void beacon_kernel(float* __restrict__ out, int n) {
  int i = blockIdx.x * 256 + threadIdx.x;
  if (i < n) out[i] = 4000.0f;
}

// C = A[M,K](bf16,lda) * BT[N,K]^T(bf16); out fp32 (Cf) or bf16 (Cb).
__global__ __launch_bounds__(64) void gemm_bt(const u16* __restrict__ A,
                                              const u16* __restrict__ BT,
                                              float* __restrict__ Cf,
                                              u16* __restrict__ Cb,
                                              int K, int lda, int ldc, int out_bf16) {
  const int bm = blockIdx.x * 64, bn = blockIdx.y * 64;
  const int lane = threadIdx.x;
  const int quad = lane >> 4, r = lane & 15;
  f32x4 acc[4][4] = {};
  const u16* ap = A  + (size_t)(bm + r) * lda + quad * 8;
  const u16* bp = BT + (size_t)(bn + r) * K   + quad * 8;
  for (int ks = 0; ks < K; ks += 32) {
    bf16x8 a[4], b[4];
#pragma unroll
    for (int i = 0; i < 4; i++)
      a[i] = *(const bf16x8*)(ap + (size_t)i * 16 * lda + ks);
#pragma unroll
    for (int j = 0; j < 4; j++)
      b[j] = *(const bf16x8*)(bp + (size_t)j * 16 * K + ks);
#pragma unroll
    for (int i = 0; i < 4; i++)
#pragma unroll
      for (int j = 0; j < 4; j++)
        acc[i][j] = __builtin_amdgcn_mfma_f32_16x16x32_bf16(a[i], b[j], acc[i][j], 0, 0, 0);
  }
#pragma unroll
  for (int i = 0; i < 4; i++)
#pragma unroll
    for (int j = 0; j < 4; j++)
#pragma unroll
      for (int rg = 0; rg < 4; rg++) {
        int row = bm + i * 16 + quad * 4 + rg;
        int col = bn + j * 16 + r;
        float v = acc[i][j][rg];
        if (out_bf16) Cb[(size_t)row * ldc + col] = f2bf(v);
        else          Cf[(size_t)row * ldc + col] = v;
      }
}

__global__ __launch_bounds__(64) void prep_kernel(float* __restrict__ P,
    const float* __restrict__ A_log, const float* __restrict__ dt_bias,
    float* __restrict__ betab, float* __restrict__ gbuf) {
  const int t = blockIdx.x >> 4, h = blockIdx.x & 15, lane = threadIdx.x;
  float* Pt = P + (size_t)t * NP;
  float qv = Pt[h * 64 + lane];
  float ss = qv * qv;
#pragma unroll
  for (int off = 32; off; off >>= 1) ss += __shfl_xor(ss, off);
  Pt[h * 64 + lane] = qv * rsqrtf(ss + 1e-6f) * 0.125f;
#pragma unroll
  for (int nh = 0; nh < 2; nh++) {
    float kv = Pt[1024 + nh * 1024 + h * 64 + lane];
    float ks = kv * kv;
#pragma unroll
    for (int off = 32; off; off >>= 1) ks += __shfl_xor(ks, off);
    Pt[1024 + nh * 1024 + h * 64 + lane] = kv * rsqrtf(ks + 1e-6f);
  }
  if (lane < 2) {
    float bb = Pt[5120 + lane * 16 + h];
    betab[(size_t)(2 * t + lane) * 16 + h] = 2.f / (1.f + expf(-bb));
  }
  if (lane == 0) {
    float a = Pt[5152 + h] + dt_bias[h];
    float sp = (a > 20.f) ? a : log1pf(expf(a));
    gbuf[t * 16 + h] = -expf(A_log[h]) * sp;
  }
}

// phase A (register-blocked): per (c,h): G, T, W(bf16), M(fp32), Uv(bf16),
// N(fp32), cum. Thread tile = 4x4 outputs; float4 LDS operand reads.
__global__ __launch_bounds__(256) void phaseA_kernel(const float* __restrict__ P,
    const float* __restrict__ betab, const float* __restrict__ gbuf,
    u16* __restrict__ Wbuf, u16* __restrict__ Uvbuf,
    float* __restrict__ Mbuf, float* __restrict__ Nbuf, float* __restrict__ cumbuf) {
  const int c = blockIdx.x, h = blockIdx.y, tid = threadIdx.x;
  const int bi = tid >> 4, bj = tid & 15;       // 4-row / 4-col output blocks
  __shared__ float kf[64][68];   // k rows [i][d]
  __shared__ float kT[64][68];   // [d][i]; later vf [j][d]
  __shared__ float Tt[64][68];   // Tt[j][i] = T[i][j]
  __shared__ float Sc[64][68];   // Ach [i][j] -> Wl [i][d] -> Uvl [i][d]
  __shared__ float cumch[64], betach[64], bbch[64], rowfl[64];
  const size_t base = ((size_t)c * 16 + h) * 4096;

  for (int e = tid; e < 4096; e += 256) {
    int i = e >> 6, d = e & 63, s = c * 64 + i, t = s >> 1, nh = s & 1;
    float kv = P[(size_t)t * NP + 1024 + nh * 1024 + h * 64 + d];
    kf[i][d] = kv; kT[d][i] = kv;
  }
  if (tid < 64) betach[tid] = betab[(size_t)(c * 64 + tid) * 16 + h];
  __syncthreads();
  if (tid == 0) {
    float cum = 0.f;
    for (int i = 0; i < 64; i++) {
      if ((i & 1) == 0) cum += gbuf[(c * 32 + (i >> 1)) * 16 + h];
      cumch[i] = cum;
    }
  }
  __syncthreads();
  if (tid < 64) {
    bbch[tid] = betach[tid] * expf(cumch[tid]);
    rowfl[tid] = expf(cumch[63] - cumch[tid]);
  }
  // G[i][j] = sum_d k[i][d]k[j][d]  (kT only), then scale -> Ach (Sc)
  {
    float acc[4][4] = {};
    for (int d = 0; d < 64; d++) {
      f32x4 a = *(const f32x4*)&kT[d][4 * bi];
      f32x4 b = *(const f32x4*)&kT[d][4 * bj];
#pragma unroll
      for (int rr = 0; rr < 4; rr++)
#pragma unroll
        for (int cc = 0; cc < 4; cc++) acc[rr][cc] += a[rr] * b[cc];
    }
#pragma unroll
    for (int rr = 0; rr < 4; rr++)
#pragma unroll
      for (int cc = 0; cc < 4; cc++) {
        int i = 4 * bi + rr, j = 4 * bj + cc;
        Sc[i][j] = (j < i) ? betach[i] * expf(cumch[i] - cumch[j]) * acc[rr][cc] : 0.f;
      }
  }
  __syncthreads();
  // T = (I+A)^-1 forward substitution -> Tt[j][i] = T[i][j]
  {
    int col = tid >> 2, part = tid & 3;
    if (part == 0) Tt[col][0] = (col == 0) ? 1.f : 0.f;
    for (int i = 1; i < 64; i++) {
      float partial = 0.f;
      for (int j = col + part; j < i; j += 4) partial += Sc[i][j] * Tt[col][j];
      partial += __shfl_xor(partial, 1);
      partial += __shfl_xor(partial, 2);
      if (part == 0) Tt[col][i] = ((i == col) ? 1.f : 0.f) - partial;
    }
  }
  __syncthreads();
  // stage v over kT region
  for (int e = tid; e < 4096; e += 256) {
    int i = e >> 6, d = e & 63, s = c * 64 + i, t = s >> 1, nh = s & 1;
    kT[i][d] = P[(size_t)t * NP + 3072 + nh * 1024 + h * 64 + d];
  }
  // W[i][d] = sum_j T[i][j]*bb[j]*k[j][d]  -> Sc + Wbuf(bf16)
  {
    float acc[4][4] = {};
    for (int j = 0; j < 64; j++) {
      f32x4 tv = *(const f32x4*)&Tt[j][4 * bi];
      f32x4 kv = *(const f32x4*)&kf[j][4 * bj];
      float bbj = bbch[j];
#pragma unroll
      for (int rr = 0; rr < 4; rr++)
#pragma unroll
        for (int cc = 0; cc < 4; cc++) acc[rr][cc] += tv[rr] * bbj * kv[cc];
    }
#pragma unroll
    for (int rr = 0; rr < 4; rr++) {
      int i = 4 * bi + rr;
      u16x4 wb;
#pragma unroll
      for (int cc = 0; cc < 4; cc++) { Sc[i][4 * bj + cc] = acc[rr][cc]; wb[cc] = f2bf(acc[rr][cc]); }
      *(u16x4*)&Wbuf[base + (size_t)i * 64 + 4 * bj] = wb;
    }
  }
  __syncthreads();
  // M[m][mm] = bL*delta - sum_i rowf[i]*k[i][m]*W[i][mm]
  {
    const float bL = expf(cumch[63]);
    float acc[4][4] = {};
    for (int i = 0; i < 64; i++) {
      f32x4 kv = *(const f32x4*)&kf[i][4 * bi];
      f32x4 wv = *(const f32x4*)&Sc[i][4 * bj];
      float rf = rowfl[i];
#pragma unroll
      for (int rr = 0; rr < 4; rr++)
#pragma unroll
        for (int cc = 0; cc < 4; cc++) acc[rr][cc] += rf * kv[rr] * wv[cc];
    }
#pragma unroll
    for (int rr = 0; rr < 4; rr++) {
      int m = 4 * bi + rr;
      f32x4 mv;
#pragma unroll
      for (int cc = 0; cc < 4; cc++)
        mv[cc] = ((m == 4 * bj + cc) ? bL : 0.f) - acc[rr][cc];
      *(f32x4*)&Mbuf[base + (size_t)m * 64 + 4 * bj] = mv;
    }
  }
  __syncthreads();
  // Uv[i][d] = sum_j T[i][j]*beta[j]*v[j][d] -> Sc + Uvbuf(bf16)
  {
    float acc[4][4] = {};
    for (int j = 0; j < 64; j++) {
      f32x4 tv = *(const f32x4*)&Tt[j][4 * bi];
      f32x4 vv = *(const f32x4*)&kT[j][4 * bj];
      float be = betach[j];
#pragma unroll
      for (int rr = 0; rr < 4; rr++)
#pragma unroll
        for (int cc = 0; cc < 4; cc++) acc[rr][cc] += tv[rr] * be * vv[cc];
    }
#pragma unroll
    for (int rr = 0; rr < 4; rr++) {
      int i = 4 * bi + rr;
      u16x4 ub;
#pragma unroll
      for (int cc = 0; cc < 4; cc++) { Sc[i][4 * bj + cc] = acc[rr][cc]; ub[cc] = f2bf(acc[rr][cc]); }
      *(u16x4*)&Uvbuf[base + (size_t)i * 64 + 4 * bj] = ub;
    }
  }
  __syncthreads();
  // N[m][d] = sum_i rowf[i]*k[i][m]*Uv[i][d]
  {
    float acc[4][4] = {};
    for (int i = 0; i < 64; i++) {
      f32x4 kv = *(const f32x4*)&kf[i][4 * bi];
      f32x4 uv = *(const f32x4*)&Sc[i][4 * bj];
      float rf = rowfl[i];
#pragma unroll
      for (int rr = 0; rr < 4; rr++)
#pragma unroll
        for (int cc = 0; cc < 4; cc++) acc[rr][cc] += rf * kv[rr] * uv[cc];
    }
#pragma unroll
    for (int rr = 0; rr < 4; rr++) {
      f32x4 nv;
#pragma unroll
      for (int cc = 0; cc < 4; cc++) nv[cc] = acc[rr][cc];
      *(f32x4*)&Nbuf[base + (size_t)(4 * bi + rr) * 64 + 4 * bj] = nv;
    }
  }
  if (tid < 64) cumbuf[((size_t)c * 16 + h) * 64 + tid] = cumch[tid];
}

// phase B: S_{c+1} = M_c S_c + N_c (M carries bL*I), seq; unchanged (fast).
__global__ __launch_bounds__(256) void phaseB_kernel(const float* __restrict__ Mbuf,
    const float* __restrict__ Nbuf, u16* __restrict__ S0buf) {
  const int g = blockIdx.x, h = blockIdx.y, tid = threadIdx.x;
  const int d = tid & 31, mb = (tid >> 5) * 8;
  __shared__ float Sl[64][33];
  __shared__ float Ml[64][64];
  __shared__ float Nl[64][32];
  for (int e = tid; e < 64 * 33; e += 256) ((float*)Sl)[e] = 0.f;
  const int nr = tid >> 2, ncol = (tid & 3) * 8;
  {
    const float4* Mc = (const float4*)(Mbuf + (size_t)h * 4096);
#pragma unroll
    for (int kq = 0; kq < 4; kq++) {
      int f = tid + kq * 256;
      *(float4*)&Ml[f >> 4][(f & 15) * 4] = Mc[f];
    }
    const float* Nc = Nbuf + (size_t)h * 4096;
    *(float4*)&Nl[nr][ncol]     = *(const float4*)(Nc + nr * 64 + g * 32 + ncol);
    *(float4*)&Nl[nr][ncol + 4] = *(const float4*)(Nc + nr * 64 + g * 32 + ncol + 4);
  }
  __syncthreads();
  for (int c = 0; c < NC; c++) {
    const size_t base = (size_t)c * 16 + h;
    float4 pm[4], pn0, pn1;
    if (c + 1 < NC) {
      const float4* Mn = (const float4*)(Mbuf + ((size_t)(c + 1) * 16 + h) * 4096);
#pragma unroll
      for (int kq = 0; kq < 4; kq++) pm[kq] = Mn[tid + kq * 256];
      const float* Nn = Nbuf + ((size_t)(c + 1) * 16 + h) * 4096;
      pn0 = *(const float4*)(Nn + nr * 64 + g * 32 + ncol);
      pn1 = *(const float4*)(Nn + nr * 64 + g * 32 + ncol + 4);
    }
    float acc[8];
#pragma unroll
    for (int j = 0; j < 8; j++) {
      float sv = Sl[mb + j][d];
      S0buf[base * 4096 + (mb + j) * 64 + g * 32 + d] = f2bf(sv);
      acc[j] = Nl[mb + j][d];
    }
    for (int mm = 0; mm < 64; mm++) {
      float s = Sl[mm][d];
#pragma unroll
      for (int j = 0; j < 8; j++) acc[j] += Ml[mb + j][mm] * s;
    }
    __syncthreads();
#pragma unroll
    for (int j = 0; j < 8; j++) Sl[mb + j][d] = acc[j];
    if (c + 1 < NC) {
#pragma unroll
      for (int kq = 0; kq < 4; kq++) {
        int f = tid + kq * 256;
        *(float4*)&Ml[f >> 4][(f & 15) * 4] = pm[kq];
      }
      *(float4*)&Nl[nr][ncol] = pn0;
      *(float4*)&Nl[nr][ncol + 4] = pn1;
    }
    __syncthreads();
  }
}

// phase B2: U = Uv - W*S0 (register-blocked, WT staged transposed)
__global__ __launch_bounds__(256) void phaseB2_kernel(const u16* __restrict__ Wbuf,
    const u16* __restrict__ S0buf, u16* __restrict__ Uvbuf) {
  const int c = blockIdx.x, h = blockIdx.y, tid = threadIdx.x;
  const int bi = tid >> 4, bd = tid & 15;
  __shared__ float WTl[64][68], S0l[64][68];
  const size_t base = ((size_t)c * 16 + h) * 4096;
  for (int e = tid; e < 4096; e += 256) {
    int i = e >> 6, m = e & 63;
    WTl[m][i] = bf2f(Wbuf[base + e]);
    S0l[i][m] = bf2f(S0buf[base + e]);
  }
  __syncthreads();
  float acc[4][4] = {};
  for (int m = 0; m < 64; m++) {
    f32x4 wv = *(const f32x4*)&WTl[m][4 * bi];
    f32x4 sv = *(const f32x4*)&S0l[m][4 * bd];
#pragma unroll
    for (int rr = 0; rr < 4; rr++)
#pragma unroll
      for (int cc = 0; cc < 4; cc++) acc[rr][cc] += wv[rr] * sv[cc];
  }
#pragma unroll
  for (int rr = 0; rr < 4; rr++) {
    int i = 4 * bi + rr;
    u16x4 uv = *(const u16x4*)&Uvbuf[base + (size_t)i * 64 + 4 * bd];
    u16x4 ob;
#pragma unroll
    for (int cc = 0; cc < 4; cc++) ob[cc] = f2bf(bf2f(uv[cc]) - acc[rr][cc]);
    *(u16x4*)&Uvbuf[base + (size_t)i * 64 + 4 * bd] = ob;
  }
}

// phase C (register-blocked): o = e^cum q.S0 + tril(decay qk^T) U, then
// RMSNorm + swish gate -> ybuf
__global__ __launch_bounds__(256) void phaseC_kernel(const float* __restrict__ P,
    const float* __restrict__ cumbuf, const u16* __restrict__ Ubuf,
    const u16* __restrict__ S0buf, const float* __restrict__ nw,
    u16* __restrict__ ybuf) {
  const int c = blockIdx.x, h = blockIdx.y, tid = threadIdx.x;
  const int rb = tid >> 4, jb = tid & 15;   // 2-row / 4-col output blocks
  __shared__ float qT[64][36];    // [d][r]; reused as ol[32][68] later
  __shared__ float kTc[64][68];   // [d][j]; reused as S0l[m][dd]
  __shared__ float Ul[64][68];    // [j][dd]
  __shared__ float PmT[64][36];   // [j][r]
  __shared__ float cuml[64], nwl[64];
  const size_t base = (size_t)c * 16 + h;
  for (int e = tid; e < 2048; e += 256) {
    int r = e >> 6, d = e & 63;
    qT[d][r] = P[(size_t)(c * 32 + r) * NP + h * 64 + d];
  }
  for (int e = tid; e < 4096; e += 256) {
    int j = e >> 6, d = e & 63, s = c * 64 + j, t = s >> 1, nh = s & 1;
    kTc[d][j] = P[(size_t)t * NP + 1024 + nh * 1024 + h * 64 + d];
    Ul[j][d] = bf2f(Ubuf[base * 4096 + e]);
  }
  if (tid < 64) { cuml[tid] = cumbuf[base * 64 + tid]; nwl[tid] = nw[tid]; }
  __syncthreads();
  // Pm[r][j] = exp(cum_{2r+1}-cum_j)*(q_r.k_j), j<=2r+1 -> PmT[j][r]
  {
    float pa[2][4] = {};
    for (int d = 0; d < 64; d++) {
      f32x2 qv = *(const f32x2*)&qT[d][2 * rb];
      f32x4 kv = *(const f32x4*)&kTc[d][4 * jb];
#pragma unroll
      for (int rr = 0; rr < 2; rr++)
#pragma unroll
        for (int cc = 0; cc < 4; cc++) pa[rr][cc] += qv[rr] * kv[cc];
    }
#pragma unroll
    for (int rr = 0; rr < 2; rr++)
#pragma unroll
      for (int cc = 0; cc < 4; cc++) {
        int r = 2 * rb + rr, i = 2 * r + 1, j = 4 * jb + cc;
        PmT[j][r] = (j <= i) ? expf(cuml[i] - cuml[j]) * pa[rr][cc] : 0.f;
      }
  }
  __syncthreads();
  for (int e = tid; e < 4096; e += 256)   // S0 over kTc
    kTc[e >> 6][e & 63] = bf2f(S0buf[base * 4096 + e]);
  __syncthreads();
  float o[2][4];
  {
    float a1[2][4] = {}, a2[2][4] = {};
    for (int m = 0; m < 64; m++) {
      f32x2 qv = *(const f32x2*)&qT[m][2 * rb];
      f32x4 sv = *(const f32x4*)&kTc[m][4 * jb];
#pragma unroll
      for (int rr = 0; rr < 2; rr++)
#pragma unroll
        for (int cc = 0; cc < 4; cc++) a1[rr][cc] += qv[rr] * sv[cc];
    }
    for (int j = 0; j < 64; j++) {
      f32x2 pv = *(const f32x2*)&PmT[j][2 * rb];
      f32x4 uv = *(const f32x4*)&Ul[j][4 * jb];
#pragma unroll
      for (int rr = 0; rr < 2; rr++)
#pragma unroll
        for (int cc = 0; cc < 4; cc++) a2[rr][cc] += pv[rr] * uv[cc];
    }
#pragma unroll
    for (int rr = 0; rr < 2; rr++) {
      float ec = expf(cuml[2 * (2 * rb + rr) + 1]);
#pragma unroll
      for (int cc = 0; cc < 4; cc++) o[rr][cc] = a1[rr][cc] * ec + a2[rr][cc];
    }
  }
  __syncthreads();   // qT dead; reuse as ol
  float* ol = &qT[0][0];   // [32][68]
#pragma unroll
  for (int rr = 0; rr < 2; rr++)
#pragma unroll
    for (int cc = 0; cc < 4; cc++)
      ol[(2 * rb + rr) * 68 + 4 * jb + cc] = o[rr][cc];
  __syncthreads();
  for (int e = tid; e < 2048; e += 256) {
    int r = e >> 6, d = e & 63;
    float ov = ol[r * 68 + d];
    float ss = ov * ov;
#pragma unroll
    for (int off = 32; off; off >>= 1) ss += __shfl_xor(ss, off);
    float on = ov * rsqrtf(ss * (1.f / 64.f) + 1e-5f) * nwl[d];
    int t = c * 32 + r;
    float gt = P[(size_t)t * NP + 5168 + h * 64 + d];
    float sw = gt / (1.f + expf(-gt));
    ybuf[(size_t)t * 1024 + h * 64 + d] = f2bf(on * sw);
  }
}

extern "C" void kernel_launch(void* const* d_in, const int* in_sizes, int n_in,
                              void* d_out, int out_size, void* d_ws, size_t ws_size,
                              hipStream_t stream) {
  const float* x       = (const float*)d_in[0];
  const float* Wq      = (const float*)d_in[1];
  const float* Wk      = (const float*)d_in[2];
  const float* Wv      = (const float*)d_in[3];
  const float* Wb      = (const float*)d_in[4];
  const float* Wa      = (const float*)d_in[5];
  const float* A_log   = (const float*)d_in[6];
  const float* dt_bias = (const float*)d_in[7];
  const float* Wg      = (const float*)d_in[8];
  const float* nw      = (const float*)d_in[9];
  const float* Wo      = (const float*)d_in[10];
  float* out = (float*)d_out;

  char* w = (char*)d_ws;
  size_t used = 0;
  auto alloc = [&](size_t bytes) {
    char* p = w + used; used += (bytes + 255) & ~(size_t)255; return p;
  };
  u16*   xb    = (u16*)  alloc(2048UL * 1024 * 2);
  u16*   WT    = (u16*)  alloc((size_t)NP * 1024 * 2);
  u16*   WoT   = (u16*)  alloc(1024UL * 1024 * 2);
  float* P     = (float*)alloc(2048UL * NP * 4);
  float* betab = (float*)alloc(4096UL * 16 * 4);
  float* gbuf  = (float*)alloc(2048UL * 16 * 4);
  u16*   ybuf  = (u16*)  alloc(2048UL * 1024 * 2);
  u16*   Wbuf  = (u16*)  alloc((size_t)NC * 16 * 4096 * 2);
  u16*   Uvbuf = (u16*)  alloc((size_t)NC * 16 * 4096 * 2);
  u16*   S0buf = (u16*)  alloc((size_t)NC * 16 * 4096 * 2);
  float* Mbuf  = (float*)alloc((size_t)NC * 16 * 4096 * 4);
  float* Nbuf  = (float*)alloc((size_t)NC * 16 * 4096 * 4);
  float* cumb  = (float*)alloc((size_t)NC * 16 * 64 * 4);

  auto tgrid = [](long n) { return dim3((unsigned)((n + 255) / 256)); };
  if (used > ws_size) {
    beacon_kernel<<<tgrid(out_size), 256, 0, stream>>>(out, out_size);
    return;
  }

  hipMemsetAsync(WT + 6192UL * 1024, 0, 16UL * 1024 * 2, stream);

  cvt_kernel<<<tgrid(2048L*1024), 256, 0, stream>>>(x, xb, 2048L * 1024);
  auto trgrid = [](int cols) { return dim3((unsigned)((cols + 31) / 32), 32); };
  transT_kernel<<<trgrid(1024), 256, 0, stream>>>(Wq, WT + 0L,         1024, 1024);
  transT_kernel<<<trgrid(2048), 256, 0, stream>>>(Wk, WT + 1024L*1024, 1024, 2048);
  transT_kernel<<<trgrid(2048), 256, 0, stream>>>(Wv, WT + 3072L*1024, 1024, 2048);
  transT_kernel<<<trgrid(32),   256, 0, stream>>>(Wb, WT + 5120L*1024, 1024, 32);
  transT_kernel<<<trgrid(16),   256, 0, stream>>>(Wa, WT + 5152L*1024, 1024, 16);
  transT_kernel<<<trgrid(1024), 256, 0, stream>>>(Wg, WT + 5168L*1024, 1024, 1024);
  transT_kernel<<<trgrid(1024), 256, 0, stream>>>(Wo, WoT,             1024, 1024);

  gemm_bt<<<dim3(32, 97), 64, 0, stream>>>(xb, WT, P, nullptr, 1024, 1024, NP, 0);
  prep_kernel<<<dim3(2048 * 16), 64, 0, stream>>>(P, A_log, dt_bias, betab, gbuf);

  phaseA_kernel<<<dim3(NC, 16), 256, 0, stream>>>(P, betab, gbuf, Wbuf, Uvbuf, Mbuf, Nbuf, cumb);
  phaseB_kernel<<<dim3(2, 16),  256, 0, stream>>>(Mbuf, Nbuf, S0buf);
  phaseB2_kernel<<<dim3(NC, 16), 256, 0, stream>>>(Wbuf, S0buf, Uvbuf);
  phaseC_kernel<<<dim3(NC, 16), 256, 0, stream>>>(P, cumb, Uvbuf, S0buf, nw, ybuf);

  gemm_bt<<<dim3(32, 16), 64, 0, stream>>>(ybuf, WoT, out, nullptr, 1024, 1024, 1024, 0);
}

// Round 9
// 729.983 us; speedup vs baseline: 1.7683x; 1.7683x over previous
//
#include <hip/hip_runtime.h>
#include <stdint.h>

// ---------------------------------------------------------------------------
// DeltaNet (gated delta rule) forward, MI355X gfx950. Round 9.
// Round 8 regressed (phaseA 406->590us): VGPR capped at 256 + 519MB scratch
// FETCH = full unroll of constant-64 matmul loops spilled accumulators.
// Fix: #pragma unroll 4 on all 64-iter matmul loops (phaseA/B2/C) and
// __launch_bounds__(256,1) on phaseA (VGPR ceiling 512 -> no spill possible).
// Math identical -> absmax must stay exactly 0.04296875.
// P column map: [0,1024) q | [1024,3072) k | [3072,5120) v |
//   [5120,5152) beta-pre | [5152,5168) a-pre | [5168,6192) gate | pad
// ---------------------------------------------------------------------------

typedef unsigned short u16;
typedef __attribute__((ext_vector_type(8))) short bf16x8;
typedef __attribute__((ext_vector_type(4))) float f32x4;
typedef __attribute__((ext_vector_type(2))) float f32x2;
typedef __attribute__((ext_vector_type(4))) unsigned short u16x4;

#define TT 2048
#define NP 6208
#define NC 64
#define CS 64

__device__ __forceinline__ u16 f2bf(float f) {
  union { float f; uint32_t u; } v; v.f = f;
  uint32_t r = v.u + 0x7fffu + ((v.u >> 16) & 1u);  // RNE
  return (u16)(r >> 16);
}
__device__ __forceinline__ float bf2f(u16 b) {
  union { uint32_t u; float f; } v; v.u = ((uint32_t)b) << 16; return v.f;
}

__global__ void cvt_kernel(const float* __restrict__ src, u16* __restrict__ dst, long n) {
  long i = (long)blockIdx.x * 256 + threadIdx.x;
  if (i < n) dst[i] = f2bf(src[i]);
}

__global__ __launch_bounds__(256) void transT_kernel(const float* __restrict__ src,
    u16* __restrict__ dst, int rows, int cols) {
  __shared__ float tile[32][33];
  const int tx = threadIdx.x & 31, ty = threadIdx.x >> 5;
  const int c0 = blockIdx.x * 32, r0 = blockIdx.y * 32;
  for (int rr = ty; rr < 32; rr += 8)
    if (c0 + tx < cols) tile[rr][tx] = src[(size_t)(r0 + rr) * cols + c0 + tx];
  __syncthreads();
  for (int rr = ty; rr < 32; rr += 8)
    if (c0 + rr < cols) dst[(size_t)(c0 + rr) * rows + r0 + tx] = f2bf(tile[tx][rr]);
}

__global__ __launch_bounds__(256) void beacon_kernel(float* __restrict__ out, int n) {
  int i = blockIdx.x * 256 + threadIdx.x;
  if (i < n) out[i] = 4000.0f;
}

// C = A[M,K](bf16,lda) * BT[N,K]^T(bf16); out fp32 (Cf) or bf16 (Cb).
__global__ __launch_bounds__(64) void gemm_bt(const u16* __restrict__ A,
                                              const u16* __restrict__ BT,
                                              float* __restrict__ Cf,
                                              u16* __restrict__ Cb,
                                              int K, int lda, int ldc, int out_bf16) {
  const int bm = blockIdx.x * 64, bn = blockIdx.y * 64;
  const int lane = threadIdx.x;
  const int quad = lane >> 4, r = lane & 15;
  f32x4 acc[4][4] = {};
  const u16* ap = A  + (size_t)(bm + r) * lda + quad * 8;
  const u16* bp = BT + (size_t)(bn + r) * K   + quad * 8;
  for (int ks = 0; ks < K; ks += 32) {
    bf16x8 a[4], b[4];
#pragma unroll
    for (int i = 0; i < 4; i++)
      a[i] = *(const bf16x8*)(ap + (size_t)i * 16 * lda + ks);
#pragma unroll
    for (int j = 0; j < 4; j++)
      b[j] = *(const bf16x8*)(bp + (size_t)j * 16 * K + ks);
#pragma unroll
    for (int i = 0; i < 4; i++)
#pragma unroll
      for (int j = 0; j < 4; j++)
        acc[i][j] = __builtin_amdgcn_mfma_f32_16x16x32_bf16(a[i], b[j], acc[i][j], 0, 0, 0);
  }
#pragma unroll
  for (int i = 0; i < 4; i++)
#pragma unroll
    for (int j = 0; j < 4; j++)
#pragma unroll
      for (int rg = 0; rg < 4; rg++) {
        int row = bm + i * 16 + quad * 4 + rg;
        int col = bn + j * 16 + r;
        float v = acc[i][j][rg];
        if (out_bf16) Cb[(size_t)row * ldc + col] = f2bf(v);
        else          Cf[(size_t)row * ldc + col] = v;
      }
}

__global__ __launch_bounds__(64) void prep_kernel(float* __restrict__ P,
    const float* __restrict__ A_log, const float* __restrict__ dt_bias,
    float* __restrict__ betab, float* __restrict__ gbuf) {
  const int t = blockIdx.x >> 4, h = blockIdx.x & 15, lane = threadIdx.x;
  float* Pt = P + (size_t)t * NP;
  float qv = Pt[h * 64 + lane];
  float ss = qv * qv;
#pragma unroll
  for (int off = 32; off; off >>= 1) ss += __shfl_xor(ss, off);
  Pt[h * 64 + lane] = qv * rsqrtf(ss + 1e-6f) * 0.125f;
#pragma unroll
  for (int nh = 0; nh < 2; nh++) {
    float kv = Pt[1024 + nh * 1024 + h * 64 + lane];
    float ks = kv * kv;
#pragma unroll
    for (int off = 32; off; off >>= 1) ks += __shfl_xor(ks, off);
    Pt[1024 + nh * 1024 + h * 64 + lane] = kv * rsqrtf(ks + 1e-6f);
  }
  if (lane < 2) {
    float bb = Pt[5120 + lane * 16 + h];
    betab[(size_t)(2 * t + lane) * 16 + h] = 2.f / (1.f + expf(-bb));
  }
  if (lane == 0) {
    float a = Pt[5152 + h] + dt_bias[h];
    float sp = (a > 20.f) ? a : log1pf(expf(a));
    gbuf[t * 16 + h] = -expf(A_log[h]) * sp;
  }
}

// phase A (register-blocked, bounded unroll): per (c,h): G, T, W(bf16),
// M(fp32), Uv(bf16), N(fp32), cum. Thread tile = 4x4; f32x4 LDS reads.
__global__ __launch_bounds__(256, 1) void phaseA_kernel(const float* __restrict__ P,
    const float* __restrict__ betab, const float* __restrict__ gbuf,
    u16* __restrict__ Wbuf, u16* __restrict__ Uvbuf,
    float* __restrict__ Mbuf, float* __restrict__ Nbuf, float* __restrict__ cumbuf) {
  const int c = blockIdx.x, h = blockIdx.y, tid = threadIdx.x;
  const int bi = tid >> 4, bj = tid & 15;
  __shared__ float kf[64][68];   // k rows [i][d]
  __shared__ float kT[64][68];   // [d][i]; later vf [j][d]
  __shared__ float Tt[64][68];   // Tt[j][i] = T[i][j]
  __shared__ float Sc[64][68];   // Ach -> Wl -> Uvl
  __shared__ float cumch[64], betach[64], bbch[64], rowfl[64];
  const size_t base = ((size_t)c * 16 + h) * 4096;

  for (int e = tid; e < 4096; e += 256) {
    int i = e >> 6, d = e & 63, s = c * 64 + i, t = s >> 1, nh = s & 1;
    float kv = P[(size_t)t * NP + 1024 + nh * 1024 + h * 64 + d];
    kf[i][d] = kv; kT[d][i] = kv;
  }
  if (tid < 64) betach[tid] = betab[(size_t)(c * 64 + tid) * 16 + h];
  __syncthreads();
  if (tid == 0) {
    float cum = 0.f;
    for (int i = 0; i < 64; i++) {
      if ((i & 1) == 0) cum += gbuf[(c * 32 + (i >> 1)) * 16 + h];
      cumch[i] = cum;
    }
  }
  __syncthreads();
  if (tid < 64) {
    bbch[tid] = betach[tid] * expf(cumch[tid]);
    rowfl[tid] = expf(cumch[63] - cumch[tid]);
  }
  // G[i][j] = sum_d k[i][d]k[j][d], then scale -> Sc
  {
    float acc[4][4] = {};
#pragma unroll 4
    for (int d = 0; d < 64; d++) {
      f32x4 a = *(const f32x4*)&kT[d][4 * bi];
      f32x4 b = *(const f32x4*)&kT[d][4 * bj];
#pragma unroll
      for (int rr = 0; rr < 4; rr++)
#pragma unroll
        for (int cc = 0; cc < 4; cc++) acc[rr][cc] += a[rr] * b[cc];
    }
#pragma unroll
    for (int rr = 0; rr < 4; rr++)
#pragma unroll
      for (int cc = 0; cc < 4; cc++) {
        int i = 4 * bi + rr, j = 4 * bj + cc;
        Sc[i][j] = (j < i) ? betach[i] * expf(cumch[i] - cumch[j]) * acc[rr][cc] : 0.f;
      }
  }
  __syncthreads();
  // T = (I+A)^-1 forward substitution -> Tt[j][i] = T[i][j]
  {
    int col = tid >> 2, part = tid & 3;
    if (part == 0) Tt[col][0] = (col == 0) ? 1.f : 0.f;
    for (int i = 1; i < 64; i++) {
      float partial = 0.f;
      for (int j = col + part; j < i; j += 4) partial += Sc[i][j] * Tt[col][j];
      partial += __shfl_xor(partial, 1);
      partial += __shfl_xor(partial, 2);
      if (part == 0) Tt[col][i] = ((i == col) ? 1.f : 0.f) - partial;
    }
  }
  __syncthreads();
  // stage v over kT region
  for (int e = tid; e < 4096; e += 256) {
    int i = e >> 6, d = e & 63, s = c * 64 + i, t = s >> 1, nh = s & 1;
    kT[i][d] = P[(size_t)t * NP + 3072 + nh * 1024 + h * 64 + d];
  }
  // W[i][d] = sum_j T[i][j]*bb[j]*k[j][d]  -> Sc + Wbuf(bf16)
  {
    float acc[4][4] = {};
#pragma unroll 4
    for (int j = 0; j < 64; j++) {
      f32x4 tv = *(const f32x4*)&Tt[j][4 * bi];
      f32x4 kv = *(const f32x4*)&kf[j][4 * bj];
      float bbj = bbch[j];
#pragma unroll
      for (int rr = 0; rr < 4; rr++)
#pragma unroll
        for (int cc = 0; cc < 4; cc++) acc[rr][cc] += tv[rr] * bbj * kv[cc];
    }
#pragma unroll
    for (int rr = 0; rr < 4; rr++) {
      int i = 4 * bi + rr;
      u16x4 wb;
#pragma unroll
      for (int cc = 0; cc < 4; cc++) { Sc[i][4 * bj + cc] = acc[rr][cc]; wb[cc] = f2bf(acc[rr][cc]); }
      *(u16x4*)&Wbuf[base + (size_t)i * 64 + 4 * bj] = wb;
    }
  }
  __syncthreads();
  // M[m][mm] = bL*delta - sum_i rowf[i]*k[i][m]*W[i][mm]
  {
    const float bL = expf(cumch[63]);
    float acc[4][4] = {};
#pragma unroll 4
    for (int i = 0; i < 64; i++) {
      f32x4 kv = *(const f32x4*)&kf[i][4 * bi];
      f32x4 wv = *(const f32x4*)&Sc[i][4 * bj];
      float rf = rowfl[i];
#pragma unroll
      for (int rr = 0; rr < 4; rr++)
#pragma unroll
        for (int cc = 0; cc < 4; cc++) acc[rr][cc] += rf * kv[rr] * wv[cc];
    }
#pragma unroll
    for (int rr = 0; rr < 4; rr++) {
      int m = 4 * bi + rr;
      f32x4 mv;
#pragma unroll
      for (int cc = 0; cc < 4; cc++)
        mv[cc] = ((m == 4 * bj + cc) ? bL : 0.f) - acc[rr][cc];
      *(f32x4*)&Mbuf[base + (size_t)m * 64 + 4 * bj] = mv;
    }
  }
  __syncthreads();
  // Uv[i][d] = sum_j T[i][j]*beta[j]*v[j][d] -> Sc + Uvbuf(bf16)
  {
    float acc[4][4] = {};
#pragma unroll 4
    for (int j = 0; j < 64; j++) {
      f32x4 tv = *(const f32x4*)&Tt[j][4 * bi];
      f32x4 vv = *(const f32x4*)&kT[j][4 * bj];
      float be = betach[j];
#pragma unroll
      for (int rr = 0; rr < 4; rr++)
#pragma unroll
        for (int cc = 0; cc < 4; cc++) acc[rr][cc] += tv[rr] * be * vv[cc];
    }
#pragma unroll
    for (int rr = 0; rr < 4; rr++) {
      int i = 4 * bi + rr;
      u16x4 ub;
#pragma unroll
      for (int cc = 0; cc < 4; cc++) { Sc[i][4 * bj + cc] = acc[rr][cc]; ub[cc] = f2bf(acc[rr][cc]); }
      *(u16x4*)&Uvbuf[base + (size_t)i * 64 + 4 * bj] = ub;
    }
  }
  __syncthreads();
  // N[m][d] = sum_i rowf[i]*k[i][m]*Uv[i][d]
  {
    float acc[4][4] = {};
#pragma unroll 4
    for (int i = 0; i < 64; i++) {
      f32x4 kv = *(const f32x4*)&kf[i][4 * bi];
      f32x4 uv = *(const f32x4*)&Sc[i][4 * bj];
      float rf = rowfl[i];
#pragma unroll
      for (int rr = 0; rr < 4; rr++)
#pragma unroll
        for (int cc = 0; cc < 4; cc++) acc[rr][cc] += rf * kv[rr] * uv[cc];
    }
#pragma unroll
    for (int rr = 0; rr < 4; rr++) {
      f32x4 nv;
#pragma unroll
      for (int cc = 0; cc < 4; cc++) nv[cc] = acc[rr][cc];
      *(f32x4*)&Nbuf[base + (size_t)(4 * bi + rr) * 64 + 4 * bj] = nv;
    }
  }
  if (tid < 64) cumbuf[((size_t)c * 16 + h) * 64 + tid] = cumch[tid];
}

// phase B: S_{c+1} = M_c S_c + N_c (M carries bL*I), seq over chunks.
__global__ __launch_bounds__(256) void phaseB_kernel(const float* __restrict__ Mbuf,
    const float* __restrict__ Nbuf, u16* __restrict__ S0buf) {
  const int g = blockIdx.x, h = blockIdx.y, tid = threadIdx.x;
  const int d = tid & 31, mb = (tid >> 5) * 8;
  __shared__ float Sl[64][33];
  __shared__ float Ml[64][64];
  __shared__ float Nl[64][32];
  for (int e = tid; e < 64 * 33; e += 256) ((float*)Sl)[e] = 0.f;
  const int nr = tid >> 2, ncol = (tid & 3) * 8;
  {
    const float4* Mc = (const float4*)(Mbuf + (size_t)h * 4096);
#pragma unroll
    for (int kq = 0; kq < 4; kq++) {
      int f = tid + kq * 256;
      *(float4*)&Ml[f >> 4][(f & 15) * 4] = Mc[f];
    }
    const float* Nc = Nbuf + (size_t)h * 4096;
    *(float4*)&Nl[nr][ncol]     = *(const float4*)(Nc + nr * 64 + g * 32 + ncol);
    *(float4*)&Nl[nr][ncol + 4] = *(const float4*)(Nc + nr * 64 + g * 32 + ncol + 4);
  }
  __syncthreads();
  for (int c = 0; c < NC; c++) {
    const size_t base = (size_t)c * 16 + h;
    float4 pm[4], pn0, pn1;
    if (c + 1 < NC) {
      const float4* Mn = (const float4*)(Mbuf + ((size_t)(c + 1) * 16 + h) * 4096);
#pragma unroll
      for (int kq = 0; kq < 4; kq++) pm[kq] = Mn[tid + kq * 256];
      const float* Nn = Nbuf + ((size_t)(c + 1) * 16 + h) * 4096;
      pn0 = *(const float4*)(Nn + nr * 64 + g * 32 + ncol);
      pn1 = *(const float4*)(Nn + nr * 64 + g * 32 + ncol + 4);
    }
    float acc[8];
#pragma unroll
    for (int j = 0; j < 8; j++) {
      float sv = Sl[mb + j][d];
      S0buf[base * 4096 + (mb + j) * 64 + g * 32 + d] = f2bf(sv);
      acc[j] = Nl[mb + j][d];
    }
#pragma unroll 8
    for (int mm = 0; mm < 64; mm++) {
      float s = Sl[mm][d];
#pragma unroll
      for (int j = 0; j < 8; j++) acc[j] += Ml[mb + j][mm] * s;
    }
    __syncthreads();
#pragma unroll
    for (int j = 0; j < 8; j++) Sl[mb + j][d] = acc[j];
    if (c + 1 < NC) {
#pragma unroll
      for (int kq = 0; kq < 4; kq++) {
        int f = tid + kq * 256;
        *(float4*)&Ml[f >> 4][(f & 15) * 4] = pm[kq];
      }
      *(float4*)&Nl[nr][ncol] = pn0;
      *(float4*)&Nl[nr][ncol + 4] = pn1;
    }
    __syncthreads();
  }
}

// phase B2: U = Uv - W*S0 (register-blocked, WT staged transposed)
__global__ __launch_bounds__(256) void phaseB2_kernel(const u16* __restrict__ Wbuf,
    const u16* __restrict__ S0buf, u16* __restrict__ Uvbuf) {
  const int c = blockIdx.x, h = blockIdx.y, tid = threadIdx.x;
  const int bi = tid >> 4, bd = tid & 15;
  __shared__ float WTl[64][68], S0l[64][68];
  const size_t base = ((size_t)c * 16 + h) * 4096;
  for (int e = tid; e < 4096; e += 256) {
    int i = e >> 6, m = e & 63;
    WTl[m][i] = bf2f(Wbuf[base + e]);
    S0l[i][m] = bf2f(S0buf[base + e]);
  }
  __syncthreads();
  float acc[4][4] = {};
#pragma unroll 4
  for (int m = 0; m < 64; m++) {
    f32x4 wv = *(const f32x4*)&WTl[m][4 * bi];
    f32x4 sv = *(const f32x4*)&S0l[m][4 * bd];
#pragma unroll
    for (int rr = 0; rr < 4; rr++)
#pragma unroll
      for (int cc = 0; cc < 4; cc++) acc[rr][cc] += wv[rr] * sv[cc];
  }
#pragma unroll
  for (int rr = 0; rr < 4; rr++) {
    int i = 4 * bi + rr;
    u16x4 uv = *(const u16x4*)&Uvbuf[base + (size_t)i * 64 + 4 * bd];
    u16x4 ob;
#pragma unroll
    for (int cc = 0; cc < 4; cc++) ob[cc] = f2bf(bf2f(uv[cc]) - acc[rr][cc]);
    *(u16x4*)&Uvbuf[base + (size_t)i * 64 + 4 * bd] = ob;
  }
}

// phase C (register-blocked, bounded unroll): o = e^cum q.S0 + tril U-path,
// fused RMSNorm + swish gate -> ybuf
__global__ __launch_bounds__(256) void phaseC_kernel(const float* __restrict__ P,
    const float* __restrict__ cumbuf, const u16* __restrict__ Ubuf,
    const u16* __restrict__ S0buf, const float* __restrict__ nw,
    u16* __restrict__ ybuf) {
  const int c = blockIdx.x, h = blockIdx.y, tid = threadIdx.x;
  const int rb = tid >> 4, jb = tid & 15;
  __shared__ float qT[64][36];    // [d][r]; reused as ol[32][68]
  __shared__ float kTc[64][68];   // [d][j]; reused as S0l
  __shared__ float Ul[64][68];
  __shared__ float PmT[64][36];
  __shared__ float cuml[64], nwl[64];
  const size_t base = (size_t)c * 16 + h;
  for (int e = tid; e < 2048; e += 256) {
    int r = e >> 6, d = e & 63;
    qT[d][r] = P[(size_t)(c * 32 + r) * NP + h * 64 + d];
  }
  for (int e = tid; e < 4096; e += 256) {
    int j = e >> 6, d = e & 63, s = c * 64 + j, t = s >> 1, nh = s & 1;
    kTc[d][j] = P[(size_t)t * NP + 1024 + nh * 1024 + h * 64 + d];
    Ul[j][d] = bf2f(Ubuf[base * 4096 + e]);
  }
  if (tid < 64) { cuml[tid] = cumbuf[base * 64 + tid]; nwl[tid] = nw[tid]; }
  __syncthreads();
  // Pm[r][j] = exp(cum_{2r+1}-cum_j)*(q_r.k_j), j<=2r+1 -> PmT[j][r]
  {
    float pa[2][4] = {};
#pragma unroll 4
    for (int d = 0; d < 64; d++) {
      f32x2 qv = *(const f32x2*)&qT[d][2 * rb];
      f32x4 kv = *(const f32x4*)&kTc[d][4 * jb];
#pragma unroll
      for (int rr = 0; rr < 2; rr++)
#pragma unroll
        for (int cc = 0; cc < 4; cc++) pa[rr][cc] += qv[rr] * kv[cc];
    }
#pragma unroll
    for (int rr = 0; rr < 2; rr++)
#pragma unroll
      for (int cc = 0; cc < 4; cc++) {
        int r = 2 * rb + rr, i = 2 * r + 1, j = 4 * jb + cc;
        PmT[j][r] = (j <= i) ? expf(cuml[i] - cuml[j]) * pa[rr][cc] : 0.f;
      }
  }
  __syncthreads();
  for (int e = tid; e < 4096; e += 256)
    kTc[e >> 6][e & 63] = bf2f(S0buf[base * 4096 + e]);
  __syncthreads();
  float o[2][4];
  {
    float a1[2][4] = {}, a2[2][4] = {};
#pragma unroll 4
    for (int m = 0; m < 64; m++) {
      f32x2 qv = *(const f32x2*)&qT[m][2 * rb];
      f32x4 sv = *(const f32x4*)&kTc[m][4 * jb];
#pragma unroll
      for (int rr = 0; rr < 2; rr++)
#pragma unroll
        for (int cc = 0; cc < 4; cc++) a1[rr][cc] += qv[rr] * sv[cc];
    }
#pragma unroll 4
    for (int j = 0; j < 64; j++) {
      f32x2 pv = *(const f32x2*)&PmT[j][2 * rb];
      f32x4 uv = *(const f32x4*)&Ul[j][4 * jb];
#pragma unroll
      for (int rr = 0; rr < 2; rr++)
#pragma unroll
        for (int cc = 0; cc < 4; cc++) a2[rr][cc] += pv[rr] * uv[cc];
    }
#pragma unroll
    for (int rr = 0; rr < 2; rr++) {
      float ec = expf(cuml[2 * (2 * rb + rr) + 1]);
#pragma unroll
      for (int cc = 0; cc < 4; cc++) o[rr][cc] = a1[rr][cc] * ec + a2[rr][cc];
    }
  }
  __syncthreads();
  float* ol = &qT[0][0];   // [32][68]
#pragma unroll
  for (int rr = 0; rr < 2; rr++)
#pragma unroll
    for (int cc = 0; cc < 4; cc++)
      ol[(2 * rb + rr) * 68 + 4 * jb + cc] = o[rr][cc];
  __syncthreads();
  for (int e = tid; e < 2048; e += 256) {
    int r = e >> 6, d = e & 63;
    float ov = ol[r * 68 + d];
    float ss = ov * ov;
#pragma unroll
    for (int off = 32; off; off >>= 1) ss += __shfl_xor(ss, off);
    float on = ov * rsqrtf(ss * (1.f / 64.f) + 1e-5f) * nwl[d];
    int t = c * 32 + r;
    float gt = P[(size_t)t * NP + 5168 + h * 64 + d];
    float sw = gt / (1.f + expf(-gt));
    ybuf[(size_t)t * 1024 + h * 64 + d] = f2bf(on * sw);
  }
}

extern "C" void kernel_launch(void* const* d_in, const int* in_sizes, int n_in,
                              void* d_out, int out_size, void* d_ws, size_t ws_size,
                              hipStream_t stream) {
  const float* x       = (const float*)d_in[0];
  const float* Wq      = (const float*)d_in[1];
  const float* Wk      = (const float*)d_in[2];
  const float* Wv      = (const float*)d_in[3];
  const float* Wb      = (const float*)d_in[4];
  const float* Wa      = (const float*)d_in[5];
  const float* A_log   = (const float*)d_in[6];
  const float* dt_bias = (const float*)d_in[7];
  const float* Wg      = (const float*)d_in[8];
  const float* nw      = (const float*)d_in[9];
  const float* Wo      = (const float*)d_in[10];
  float* out = (float*)d_out;

  char* w = (char*)d_ws;
  size_t used = 0;
  auto alloc = [&](size_t bytes) {
    char* p = w + used; used += (bytes + 255) & ~(size_t)255; return p;
  };
  u16*   xb    = (u16*)  alloc(2048UL * 1024 * 2);
  u16*   WT    = (u16*)  alloc((size_t)NP * 1024 * 2);
  u16*   WoT   = (u16*)  alloc(1024UL * 1024 * 2);
  float* P     = (float*)alloc(2048UL * NP * 4);
  float* betab = (float*)alloc(4096UL * 16 * 4);
  float* gbuf  = (float*)alloc(2048UL * 16 * 4);
  u16*   ybuf  = (u16*)  alloc(2048UL * 1024 * 2);
  u16*   Wbuf  = (u16*)  alloc((size_t)NC * 16 * 4096 * 2);
  u16*   Uvbuf = (u16*)  alloc((size_t)NC * 16 * 4096 * 2);
  u16*   S0buf = (u16*)  alloc((size_t)NC * 16 * 4096 * 2);
  float* Mbuf  = (float*)alloc((size_t)NC * 16 * 4096 * 4);
  float* Nbuf  = (float*)alloc((size_t)NC * 16 * 4096 * 4);
  float* cumb  = (float*)alloc((size_t)NC * 16 * 64 * 4);

  auto tgrid = [](long n) { return dim3((unsigned)((n + 255) / 256)); };
  if (used > ws_size) {
    beacon_kernel<<<tgrid(out_size), 256, 0, stream>>>(out, out_size);
    return;
  }

  hipMemsetAsync(WT + 6192UL * 1024, 0, 16UL * 1024 * 2, stream);

  cvt_kernel<<<tgrid(2048L*1024), 256, 0, stream>>>(x, xb, 2048L * 1024);
  auto trgrid = [](int cols) { return dim3((unsigned)((cols + 31) / 32), 32); };
  transT_kernel<<<trgrid(1024), 256, 0, stream>>>(Wq, WT + 0L,         1024, 1024);
  transT_kernel<<<trgrid(2048), 256, 0, stream>>>(Wk, WT + 1024L*1024, 1024, 2048);
  transT_kernel<<<trgrid(2048), 256, 0, stream>>>(Wv, WT + 3072L*1024, 1024, 2048);
  transT_kernel<<<trgrid(32),   256, 0, stream>>>(Wb, WT + 5120L*1024, 1024, 32);
  transT_kernel<<<trgrid(16),   256, 0, stream>>>(Wa, WT + 5152L*1024, 1024, 16);
  transT_kernel<<<trgrid(1024), 256, 0, stream>>>(Wg, WT + 5168L*1024, 1024, 1024);
  transT_kernel<<<trgrid(1024), 256, 0, stream>>>(Wo, WoT,             1024, 1024);

  gemm_bt<<<dim3(32, 97), 64, 0, stream>>>(xb, WT, P, nullptr, 1024, 1024, NP, 0);
  prep_kernel<<<dim3(2048 * 16), 64, 0, stream>>>(P, A_log, dt_bias, betab, gbuf);

  phaseA_kernel<<<dim3(NC, 16), 256, 0, stream>>>(P, betab, gbuf, Wbuf, Uvbuf, Mbuf, Nbuf, cumb);
  phaseB_kernel<<<dim3(2, 16),  256, 0, stream>>>(Mbuf, Nbuf, S0buf);
  phaseB2_kernel<<<dim3(NC, 16), 256, 0, stream>>>(Wbuf, S0buf, Uvbuf);
  phaseC_kernel<<<dim3(NC, 16), 256, 0, stream>>>(P, cumb, Uvbuf, S0buf, nw, ybuf);

  gemm_bt<<<dim3(32, 16), 64, 0, stream>>>(ybuf, WoT, out, nullptr, 1024, 1024, 1024, 0);
}

// Round 10
// 682.536 us; speedup vs baseline: 1.8912x; 1.0695x over previous
//
#include <hip/hip_runtime.h>
#include <stdint.h>

// ---------------------------------------------------------------------------
// DeltaNet (gated delta rule) forward, MI355X gfx950. Round 10.
// Round 9: 730us, phaseB 307us @ occupancy 1.5% (32 blocks, scalar-LDS-bound).
// This round: phaseB rewritten column-parallel: 512 blocks (32 colpairs x 16
// heads) x 1 wave; lane l = state row l, 2 cols in regs; column state in LDS
// ping-pong read as broadcast f32x4; M rows prefetched per-lane dwordx4.
// Sum order preserved (mm ascending, acc=N) -> absmax stays 0.04296875.
// Layout changes: N stored transposed NT[d][m]; S0 stored transposed
// S0T[d][m] (coalesced stores in phaseB; consumers transpose during staging).
// P column map: [0,1024) q | [1024,3072) k | [3072,5120) v |
//   [5120,5152) beta-pre | [5152,5168) a-pre | [5168,6192) gate | pad
// ---------------------------------------------------------------------------

typedef unsigned short u16;
typedef __attribute__((ext_vector_type(8))) short bf16x8;
typedef __attribute__((ext_vector_type(4))) float f32x4;
typedef __attribute__((ext_vector_type(2))) float f32x2;
typedef __attribute__((ext_vector_type(4))) unsigned short u16x4;

#define TT 2048
#define NP 6208
#define NC 64
#define CS 64

__device__ __forceinline__ u16 f2bf(float f) {
  union { float f; uint32_t u; } v; v.f = f;
  uint32_t r = v.u + 0x7fffu + ((v.u >> 16) & 1u);  // RNE
  return (u16)(r >> 16);
}
__device__ __forceinline__ float bf2f(u16 b) {
  union { uint32_t u; float f; } v; v.u = ((uint32_t)b) << 16; return v.f;
}

__global__ void cvt_kernel(const float* __restrict__ src, u16* __restrict__ dst, long n) {
  long i = (long)blockIdx.x * 256 + threadIdx.x;
  if (i < n) dst[i] = f2bf(src[i]);
}

__global__ __launch_bounds__(256) void transT_kernel(const float* __restrict__ src,
    u16* __restrict__ dst, int rows, int cols) {
  __shared__ float tile[32][33];
  const int tx = threadIdx.x & 31, ty = threadIdx.x >> 5;
  const int c0 = blockIdx.x * 32, r0 = blockIdx.y * 32;
  for (int rr = ty; rr < 32; rr += 8)
    if (c0 + tx < cols) tile[rr][tx] = src[(size_t)(r0 + rr) * cols + c0 + tx];
  __syncthreads();
  for (int rr = ty; rr < 32; rr += 8)
    if (c0 + rr < cols) dst[(size_t)(c0 + rr) * rows + r0 + tx] = f2bf(tile[tx][rr]);
}

__global__ __launch_bounds__(256) void beacon_kernel(float* __restrict__ out, int n) {
  int i = blockIdx.x * 256 + threadIdx.x;
  if (i < n) out[i] = 4000.0f;
}

// C = A[M,K](bf16,lda) * BT[N,K]^T(bf16); out fp32 (Cf) or bf16 (Cb).
__global__ __launch_bounds__(64) void gemm_bt(const u16* __restrict__ A,
                                              const u16* __restrict__ BT,
                                              float* __restrict__ Cf,
                                              u16* __restrict__ Cb,
                                              int K, int lda, int ldc, int out_bf16) {
  const int bm = blockIdx.x * 64, bn = blockIdx.y * 64;
  const int lane = threadIdx.x;
  const int quad = lane >> 4, r = lane & 15;
  f32x4 acc[4][4] = {};
  const u16* ap = A  + (size_t)(bm + r) * lda + quad * 8;
  const u16* bp = BT + (size_t)(bn + r) * K   + quad * 8;
  for (int ks = 0; ks < K; ks += 32) {
    bf16x8 a[4], b[4];
#pragma unroll
    for (int i = 0; i < 4; i++)
      a[i] = *(const bf16x8*)(ap + (size_t)i * 16 * lda + ks);
#pragma unroll
    for (int j = 0; j < 4; j++)
      b[j] = *(const bf16x8*)(bp + (size_t)j * 16 * K + ks);
#pragma unroll
    for (int i = 0; i < 4; i++)
#pragma unroll
      for (int j = 0; j < 4; j++)
        acc[i][j] = __builtin_amdgcn_mfma_f32_16x16x32_bf16(a[i], b[j], acc[i][j], 0, 0, 0);
  }
#pragma unroll
  for (int i = 0; i < 4; i++)
#pragma unroll
    for (int j = 0; j < 4; j++)
#pragma unroll
      for (int rg = 0; rg < 4; rg++) {
        int row = bm + i * 16 + quad * 4 + rg;
        int col = bn + j * 16 + r;
        float v = acc[i][j][rg];
        if (out_bf16) Cb[(size_t)row * ldc + col] = f2bf(v);
        else          Cf[(size_t)row * ldc + col] = v;
      }
}

__global__ __launch_bounds__(64) void prep_kernel(float* __restrict__ P,
    const float* __restrict__ A_log, const float* __restrict__ dt_bias,
    float* __restrict__ betab, float* __restrict__ gbuf) {
  const int t = blockIdx.x >> 4, h = blockIdx.x & 15, lane = threadIdx.x;
  float* Pt = P + (size_t)t * NP;
  float qv = Pt[h * 64 + lane];
  float ss = qv * qv;
#pragma unroll
  for (int off = 32; off; off >>= 1) ss += __shfl_xor(ss, off);
  Pt[h * 64 + lane] = qv * rsqrtf(ss + 1e-6f) * 0.125f;
#pragma unroll
  for (int nh = 0; nh < 2; nh++) {
    float kv = Pt[1024 + nh * 1024 + h * 64 + lane];
    float ks = kv * kv;
#pragma unroll
    for (int off = 32; off; off >>= 1) ks += __shfl_xor(ks, off);
    Pt[1024 + nh * 1024 + h * 64 + lane] = kv * rsqrtf(ks + 1e-6f);
  }
  if (lane < 2) {
    float bb = Pt[5120 + lane * 16 + h];
    betab[(size_t)(2 * t + lane) * 16 + h] = 2.f / (1.f + expf(-bb));
  }
  if (lane == 0) {
    float a = Pt[5152 + h] + dt_bias[h];
    float sp = (a > 20.f) ? a : log1pf(expf(a));
    gbuf[t * 16 + h] = -expf(A_log[h]) * sp;
  }
}

// phase A: per (c,h): G, T, W(bf16), M(fp32,[m][mm]), Uv(bf16), NT(fp32,
// [d][m] transposed), cum. 4x4 register tiles, f32x4 LDS reads, unroll 4.
__global__ __launch_bounds__(256, 1) void phaseA_kernel(const float* __restrict__ P,
    const float* __restrict__ betab, const float* __restrict__ gbuf,
    u16* __restrict__ Wbuf, u16* __restrict__ Uvbuf,
    float* __restrict__ Mbuf, float* __restrict__ NTbuf, float* __restrict__ cumbuf) {
  const int c = blockIdx.x, h = blockIdx.y, tid = threadIdx.x;
  const int bi = tid >> 4, bj = tid & 15;
  __shared__ float kf[64][68];   // k rows [i][d]
  __shared__ float kT[64][68];   // [d][i]; later vf [j][d]
  __shared__ float Tt[64][68];   // Tt[j][i] = T[i][j]
  __shared__ float Sc[64][68];   // Ach -> Wl -> Uvl
  __shared__ float cumch[64], betach[64], bbch[64], rowfl[64];
  const size_t base = ((size_t)c * 16 + h) * 4096;

  for (int e = tid; e < 4096; e += 256) {
    int i = e >> 6, d = e & 63, s = c * 64 + i, t = s >> 1, nh = s & 1;
    float kv = P[(size_t)t * NP + 1024 + nh * 1024 + h * 64 + d];
    kf[i][d] = kv; kT[d][i] = kv;
  }
  if (tid < 64) betach[tid] = betab[(size_t)(c * 64 + tid) * 16 + h];
  __syncthreads();
  if (tid == 0) {
    float cum = 0.f;
    for (int i = 0; i < 64; i++) {
      if ((i & 1) == 0) cum += gbuf[(c * 32 + (i >> 1)) * 16 + h];
      cumch[i] = cum;
    }
  }
  __syncthreads();
  if (tid < 64) {
    bbch[tid] = betach[tid] * expf(cumch[tid]);
    rowfl[tid] = expf(cumch[63] - cumch[tid]);
  }
  // G[i][j] then scale -> Sc
  {
    float acc[4][4] = {};
#pragma unroll 4
    for (int d = 0; d < 64; d++) {
      f32x4 a = *(const f32x4*)&kT[d][4 * bi];
      f32x4 b = *(const f32x4*)&kT[d][4 * bj];
#pragma unroll
      for (int rr = 0; rr < 4; rr++)
#pragma unroll
        for (int cc = 0; cc < 4; cc++) acc[rr][cc] += a[rr] * b[cc];
    }
#pragma unroll
    for (int rr = 0; rr < 4; rr++)
#pragma unroll
      for (int cc = 0; cc < 4; cc++) {
        int i = 4 * bi + rr, j = 4 * bj + cc;
        Sc[i][j] = (j < i) ? betach[i] * expf(cumch[i] - cumch[j]) * acc[rr][cc] : 0.f;
      }
  }
  __syncthreads();
  // T = (I+A)^-1 forward substitution -> Tt[j][i]
  {
    int col = tid >> 2, part = tid & 3;
    if (part == 0) Tt[col][0] = (col == 0) ? 1.f : 0.f;
    for (int i = 1; i < 64; i++) {
      float partial = 0.f;
      for (int j = col + part; j < i; j += 4) partial += Sc[i][j] * Tt[col][j];
      partial += __shfl_xor(partial, 1);
      partial += __shfl_xor(partial, 2);
      if (part == 0) Tt[col][i] = ((i == col) ? 1.f : 0.f) - partial;
    }
  }
  __syncthreads();
  // stage v over kT region
  for (int e = tid; e < 4096; e += 256) {
    int i = e >> 6, d = e & 63, s = c * 64 + i, t = s >> 1, nh = s & 1;
    kT[i][d] = P[(size_t)t * NP + 3072 + nh * 1024 + h * 64 + d];
  }
  // W[i][d] = sum_j T[i][j]*bb[j]*k[j][d] -> Sc + Wbuf(bf16)
  {
    float acc[4][4] = {};
#pragma unroll 4
    for (int j = 0; j < 64; j++) {
      f32x4 tv = *(const f32x4*)&Tt[j][4 * bi];
      f32x4 kv = *(const f32x4*)&kf[j][4 * bj];
      float bbj = bbch[j];
#pragma unroll
      for (int rr = 0; rr < 4; rr++)
#pragma unroll
        for (int cc = 0; cc < 4; cc++) acc[rr][cc] += tv[rr] * bbj * kv[cc];
    }
#pragma unroll
    for (int rr = 0; rr < 4; rr++) {
      int i = 4 * bi + rr;
      u16x4 wb;
#pragma unroll
      for (int cc = 0; cc < 4; cc++) { Sc[i][4 * bj + cc] = acc[rr][cc]; wb[cc] = f2bf(acc[rr][cc]); }
      *(u16x4*)&Wbuf[base + (size_t)i * 64 + 4 * bj] = wb;
    }
  }
  __syncthreads();
  // M[m][mm] = bL*delta - sum_i rowf[i]*k[i][m]*W[i][mm]
  {
    const float bL = expf(cumch[63]);
    float acc[4][4] = {};
#pragma unroll 4
    for (int i = 0; i < 64; i++) {
      f32x4 kv = *(const f32x4*)&kf[i][4 * bi];
      f32x4 wv = *(const f32x4*)&Sc[i][4 * bj];
      float rf = rowfl[i];
#pragma unroll
      for (int rr = 0; rr < 4; rr++)
#pragma unroll
        for (int cc = 0; cc < 4; cc++) acc[rr][cc] += rf * kv[rr] * wv[cc];
    }
#pragma unroll
    for (int rr = 0; rr < 4; rr++) {
      int m = 4 * bi + rr;
      f32x4 mv;
#pragma unroll
      for (int cc = 0; cc < 4; cc++)
        mv[cc] = ((m == 4 * bj + cc) ? bL : 0.f) - acc[rr][cc];
      *(f32x4*)&Mbuf[base + (size_t)m * 64 + 4 * bj] = mv;
    }
  }
  __syncthreads();
  // Uv[i][d] = sum_j T[i][j]*beta[j]*v[j][d] -> Sc + Uvbuf(bf16)
  {
    float acc[4][4] = {};
#pragma unroll 4
    for (int j = 0; j < 64; j++) {
      f32x4 tv = *(const f32x4*)&Tt[j][4 * bi];
      f32x4 vv = *(const f32x4*)&kT[j][4 * bj];
      float be = betach[j];
#pragma unroll
      for (int rr = 0; rr < 4; rr++)
#pragma unroll
        for (int cc = 0; cc < 4; cc++) acc[rr][cc] += tv[rr] * be * vv[cc];
    }
#pragma unroll
    for (int rr = 0; rr < 4; rr++) {
      int i = 4 * bi + rr;
      u16x4 ub;
#pragma unroll
      for (int cc = 0; cc < 4; cc++) { Sc[i][4 * bj + cc] = acc[rr][cc]; ub[cc] = f2bf(acc[rr][cc]); }
      *(u16x4*)&Uvbuf[base + (size_t)i * 64 + 4 * bj] = ub;
    }
  }
  __syncthreads();
  // NT[d][m] = N[m][d] = sum_i rowf[i]*k[i][m]*Uv[i][d]   (transposed store)
  {
    float acc[4][4] = {};
#pragma unroll 4
    for (int i = 0; i < 64; i++) {
      f32x4 kv = *(const f32x4*)&kf[i][4 * bi];
      f32x4 uv = *(const f32x4*)&Sc[i][4 * bj];
      float rf = rowfl[i];
#pragma unroll
      for (int rr = 0; rr < 4; rr++)
#pragma unroll
        for (int cc = 0; cc < 4; cc++) acc[rr][cc] += rf * kv[rr] * uv[cc];
    }
#pragma unroll
    for (int cc = 0; cc < 4; cc++) {
      f32x4 nv;
#pragma unroll
      for (int rr = 0; rr < 4; rr++) nv[rr] = acc[rr][cc];   // m = 4bi+rr
      *(f32x4*)&NTbuf[base + (size_t)(4 * bj + cc) * 64 + 4 * bi] = nv;
    }
  }
  if (tid < 64) cumbuf[((size_t)c * 16 + h) * 64 + tid] = cumch[tid];
}

// phase B (column-parallel): S'[.,d] = M S[.,d] + N[.,d] per column.
// grid (32,16): colpair g, head h; 1 wave. Lane l = state row l, cols 2g,2g+1.
// Column state in LDS ping-pong (broadcast f32x4 reads); M rows prefetched.
// Stores incoming state transposed: S0T[d][m] (coalesced bf16).
__global__ __launch_bounds__(64) void phaseB_kernel(const float* __restrict__ Mbuf,
    const float* __restrict__ NTbuf, u16* __restrict__ S0Tbuf) {
  const int g = blockIdx.x, h = blockIdx.y, l = threadIdx.x;
  const int c0 = 2 * g, c1 = 2 * g + 1;
  __shared__ float Ssh[2][2][64];
  Ssh[0][0][l] = 0.f; Ssh[0][1][l] = 0.f;
  float s0 = 0.f, s1 = 0.f;
  f32x4 mreg[16];
  float n0, n1;
  {
    const float* Mc = Mbuf + (size_t)h * 4096 + (size_t)l * 64;
#pragma unroll
    for (int q = 0; q < 16; q++) mreg[q] = *(const f32x4*)(Mc + 4 * q);
    const float* Nc = NTbuf + (size_t)h * 4096;
    n0 = Nc[c0 * 64 + l]; n1 = Nc[c1 * 64 + l];
  }
  __syncthreads();
  int p = 0;
  for (int c = 0; c < NC; c++) {
    const size_t base = ((size_t)c * 16 + h) * 4096;
    // store incoming state (coalesced: 64 consecutive u16 per col)
    S0Tbuf[base + (size_t)c0 * 64 + l] = f2bf(s0);
    S0Tbuf[base + (size_t)c1 * 64 + l] = f2bf(s1);
    // prefetch next chunk
    f32x4 mnext[16]; float nn0 = 0.f, nn1 = 0.f;
    if (c + 1 < NC) {
      const float* Mn = Mbuf + ((size_t)(c + 1) * 16 + h) * 4096 + (size_t)l * 64;
#pragma unroll
      for (int q = 0; q < 16; q++) mnext[q] = *(const f32x4*)(Mn + 4 * q);
      const float* Nn = NTbuf + ((size_t)(c + 1) * 16 + h) * 4096;
      nn0 = Nn[c0 * 64 + l]; nn1 = Nn[c1 * 64 + l];
    }
    float acc0 = n0, acc1 = n1;
#pragma unroll 4
    for (int q = 0; q < 16; q++) {
      f32x4 mv = mreg[q];
      f32x4 sv0 = *(const f32x4*)&Ssh[p][0][4 * q];   // broadcast
      f32x4 sv1 = *(const f32x4*)&Ssh[p][1][4 * q];
#pragma unroll
      for (int t = 0; t < 4; t++) { acc0 += mv[t] * sv0[t]; acc1 += mv[t] * sv1[t]; }
    }
    s0 = acc0; s1 = acc1;
    Ssh[p ^ 1][0][l] = s0; Ssh[p ^ 1][1][l] = s1;
    __syncthreads();
    p ^= 1;
#pragma unroll
    for (int q = 0; q < 16; q++) mreg[q] = mnext[q];
    n0 = nn0; n1 = nn1;
  }
}

// phase B2: U = Uv - W*S0 (register-blocked; S0 staged transposed from S0T)
__global__ __launch_bounds__(256) void phaseB2_kernel(const u16* __restrict__ Wbuf,
    const u16* __restrict__ S0Tbuf, u16* __restrict__ Uvbuf) {
  const int c = blockIdx.x, h = blockIdx.y, tid = threadIdx.x;
  const int bi = tid >> 4, bd = tid & 15;
  __shared__ float WTl[64][68], S0l[64][68];
  const size_t base = ((size_t)c * 16 + h) * 4096;
  for (int e = tid; e < 4096; e += 256) {
    int i = e >> 6, m = e & 63;
    WTl[m][i] = bf2f(Wbuf[base + e]);          // W [i][m] -> WTl[m][i]
    S0l[m][i] = bf2f(S0Tbuf[base + e]);        // S0T [d][m]: i=d, m=m -> S0l[m][d]
  }
  __syncthreads();
  float acc[4][4] = {};
#pragma unroll 4
  for (int m = 0; m < 64; m++) {
    f32x4 wv = *(const f32x4*)&WTl[m][4 * bi];
    f32x4 sv = *(const f32x4*)&S0l[m][4 * bd];
#pragma unroll
    for (int rr = 0; rr < 4; rr++)
#pragma unroll
      for (int cc = 0; cc < 4; cc++) acc[rr][cc] += wv[rr] * sv[cc];
  }
#pragma unroll
  for (int rr = 0; rr < 4; rr++) {
    int i = 4 * bi + rr;
    u16x4 uv = *(const u16x4*)&Uvbuf[base + (size_t)i * 64 + 4 * bd];
    u16x4 ob;
#pragma unroll
    for (int cc = 0; cc < 4; cc++) ob[cc] = f2bf(bf2f(uv[cc]) - acc[rr][cc]);
    *(u16x4*)&Uvbuf[base + (size_t)i * 64 + 4 * bd] = ob;
  }
}

// phase C: o = e^cum q.S0 + tril(decay qk^T) U, RMSNorm+swish -> ybuf
__global__ __launch_bounds__(256) void phaseC_kernel(const float* __restrict__ P,
    const float* __restrict__ cumbuf, const u16* __restrict__ Ubuf,
    const u16* __restrict__ S0Tbuf, const float* __restrict__ nw,
    u16* __restrict__ ybuf) {
  const int c = blockIdx.x, h = blockIdx.y, tid = threadIdx.x;
  const int rb = tid >> 4, jb = tid & 15;
  __shared__ float qT[64][36];    // [d][r]; reused as ol[32][68]
  __shared__ float kTc[64][68];   // [d][j]; reused as S0l[m][d]
  __shared__ float Ul[64][68];
  __shared__ float PmT[64][36];
  __shared__ float cuml[64], nwl[64];
  const size_t base = (size_t)c * 16 + h;
  for (int e = tid; e < 2048; e += 256) {
    int r = e >> 6, d = e & 63;
    qT[d][r] = P[(size_t)(c * 32 + r) * NP + h * 64 + d];
  }
  for (int e = tid; e < 4096; e += 256) {
    int j = e >> 6, d = e & 63, s = c * 64 + j, t = s >> 1, nh = s & 1;
    kTc[d][j] = P[(size_t)t * NP + 1024 + nh * 1024 + h * 64 + d];
    Ul[j][d] = bf2f(Ubuf[base * 4096 + e]);
  }
  if (tid < 64) { cuml[tid] = cumbuf[base * 64 + tid]; nwl[tid] = nw[tid]; }
  __syncthreads();
  {
    float pa[2][4] = {};
#pragma unroll 4
    for (int d = 0; d < 64; d++) {
      f32x2 qv = *(const f32x2*)&qT[d][2 * rb];
      f32x4 kv = *(const f32x4*)&kTc[d][4 * jb];
#pragma unroll
      for (int rr = 0; rr < 2; rr++)
#pragma unroll
        for (int cc = 0; cc < 4; cc++) pa[rr][cc] += qv[rr] * kv[cc];
    }
#pragma unroll
    for (int rr = 0; rr < 2; rr++)
#pragma unroll
      for (int cc = 0; cc < 4; cc++) {
        int r = 2 * rb + rr, i = 2 * r + 1, j = 4 * jb + cc;
        PmT[j][r] = (j <= i) ? expf(cuml[i] - cuml[j]) * pa[rr][cc] : 0.f;
      }
  }
  __syncthreads();
  for (int e = tid; e < 4096; e += 256) {    // S0T [d][m] -> kTc[m][d]
    int d = e >> 6, m = e & 63;
    kTc[m][d] = bf2f(S0Tbuf[base * 4096 + e]);
  }
  __syncthreads();
  float o[2][4];
  {
    float a1[2][4] = {}, a2[2][4] = {};
#pragma unroll 4
    for (int m = 0; m < 64; m++) {
      f32x2 qv = *(const f32x2*)&qT[m][2 * rb];
      f32x4 sv = *(const f32x4*)&kTc[m][4 * jb];
#pragma unroll
      for (int rr = 0; rr < 2; rr++)
#pragma unroll
        for (int cc = 0; cc < 4; cc++) a1[rr][cc] += qv[rr] * sv[cc];
    }
#pragma unroll 4
    for (int j = 0; j < 64; j++) {
      f32x2 pv = *(const f32x2*)&PmT[j][2 * rb];
      f32x4 uv = *(const f32x4*)&Ul[j][4 * jb];
#pragma unroll
      for (int rr = 0; rr < 2; rr++)
#pragma unroll
        for (int cc = 0; cc < 4; cc++) a2[rr][cc] += pv[rr] * uv[cc];
    }
#pragma unroll
    for (int rr = 0; rr < 2; rr++) {
      float ec = expf(cuml[2 * (2 * rb + rr) + 1]);
#pragma unroll
      for (int cc = 0; cc < 4; cc++) o[rr][cc] = a1[rr][cc] * ec + a2[rr][cc];
    }
  }
  __syncthreads();
  float* ol = &qT[0][0];   // [32][68]
#pragma unroll
  for (int rr = 0; rr < 2; rr++)
#pragma unroll
    for (int cc = 0; cc < 4; cc++)
      ol[(2 * rb + rr) * 68 + 4 * jb + cc] = o[rr][cc];
  __syncthreads();
  for (int e = tid; e < 2048; e += 256) {
    int r = e >> 6, d = e & 63;
    float ov = ol[r * 68 + d];
    float ss = ov * ov;
#pragma unroll
    for (int off = 32; off; off >>= 1) ss += __shfl_xor(ss, off);
    float on = ov * rsqrtf(ss * (1.f / 64.f) + 1e-5f) * nwl[d];
    int t = c * 32 + r;
    float gt = P[(size_t)t * NP + 5168 + h * 64 + d];
    float sw = gt / (1.f + expf(-gt));
    ybuf[(size_t)t * 1024 + h * 64 + d] = f2bf(on * sw);
  }
}

extern "C" void kernel_launch(void* const* d_in, const int* in_sizes, int n_in,
                              void* d_out, int out_size, void* d_ws, size_t ws_size,
                              hipStream_t stream) {
  const float* x       = (const float*)d_in[0];
  const float* Wq      = (const float*)d_in[1];
  const float* Wk      = (const float*)d_in[2];
  const float* Wv      = (const float*)d_in[3];
  const float* Wb      = (const float*)d_in[4];
  const float* Wa      = (const float*)d_in[5];
  const float* A_log   = (const float*)d_in[6];
  const float* dt_bias = (const float*)d_in[7];
  const float* Wg      = (const float*)d_in[8];
  const float* nw      = (const float*)d_in[9];
  const float* Wo      = (const float*)d_in[10];
  float* out = (float*)d_out;

  char* w = (char*)d_ws;
  size_t used = 0;
  auto alloc = [&](size_t bytes) {
    char* p = w + used; used += (bytes + 255) & ~(size_t)255; return p;
  };
  u16*   xb    = (u16*)  alloc(2048UL * 1024 * 2);
  u16*   WT    = (u16*)  alloc((size_t)NP * 1024 * 2);
  u16*   WoT   = (u16*)  alloc(1024UL * 1024 * 2);
  float* P     = (float*)alloc(2048UL * NP * 4);
  float* betab = (float*)alloc(4096UL * 16 * 4);
  float* gbuf  = (float*)alloc(2048UL * 16 * 4);
  u16*   ybuf  = (u16*)  alloc(2048UL * 1024 * 2);
  u16*   Wbuf  = (u16*)  alloc((size_t)NC * 16 * 4096 * 2);
  u16*   Uvbuf = (u16*)  alloc((size_t)NC * 16 * 4096 * 2);
  u16*   S0Tb  = (u16*)  alloc((size_t)NC * 16 * 4096 * 2);
  float* Mbuf  = (float*)alloc((size_t)NC * 16 * 4096 * 4);
  float* NTbuf = (float*)alloc((size_t)NC * 16 * 4096 * 4);
  float* cumb  = (float*)alloc((size_t)NC * 16 * 64 * 4);

  auto tgrid = [](long n) { return dim3((unsigned)((n + 255) / 256)); };
  if (used > ws_size) {
    beacon_kernel<<<tgrid(out_size), 256, 0, stream>>>(out, out_size);
    return;
  }

  hipMemsetAsync(WT + 6192UL * 1024, 0, 16UL * 1024 * 2, stream);

  cvt_kernel<<<tgrid(2048L*1024), 256, 0, stream>>>(x, xb, 2048L * 1024);
  auto trgrid = [](int cols) { return dim3((unsigned)((cols + 31) / 32), 32); };
  transT_kernel<<<trgrid(1024), 256, 0, stream>>>(Wq, WT + 0L,         1024, 1024);
  transT_kernel<<<trgrid(2048), 256, 0, stream>>>(Wk, WT + 1024L*1024, 1024, 2048);
  transT_kernel<<<trgrid(2048), 256, 0, stream>>>(Wv, WT + 3072L*1024, 1024, 2048);
  transT_kernel<<<trgrid(32),   256, 0, stream>>>(Wb, WT + 5120L*1024, 1024, 32);
  transT_kernel<<<trgrid(16),   256, 0, stream>>>(Wa, WT + 5152L*1024, 1024, 16);
  transT_kernel<<<trgrid(1024), 256, 0, stream>>>(Wg, WT + 5168L*1024, 1024, 1024);
  transT_kernel<<<trgrid(1024), 256, 0, stream>>>(Wo, WoT,             1024, 1024);

  gemm_bt<<<dim3(32, 97), 64, 0, stream>>>(xb, WT, P, nullptr, 1024, 1024, NP, 0);
  prep_kernel<<<dim3(2048 * 16), 64, 0, stream>>>(P, A_log, dt_bias, betab, gbuf);

  phaseA_kernel<<<dim3(NC, 16), 256, 0, stream>>>(P, betab, gbuf, Wbuf, Uvbuf, Mbuf, NTbuf, cumb);
  phaseB_kernel<<<dim3(32, 16), 64, 0, stream>>>(Mbuf, NTbuf, S0Tb);
  phaseB2_kernel<<<dim3(NC, 16), 256, 0, stream>>>(Wbuf, S0Tb, Uvbuf);
  phaseC_kernel<<<dim3(NC, 16), 256, 0, stream>>>(P, cumb, Uvbuf, S0Tb, nw, ybuf);

  gemm_bt<<<dim3(32, 16), 64, 0, stream>>>(ybuf, WoT, out, nullptr, 1024, 1024, 1024, 0);
}

// Round 11
// 492.091 us; speedup vs baseline: 2.6231x; 1.3870x over previous
//
#include <hip/hip_runtime.h>
#include <stdint.h>

// ---------------------------------------------------------------------------
// DeltaNet (gated delta rule) forward, MI355X gfx950. Round 11.
// Round 10: phaseB 264us with VGPR_Count=52 -> smoking gun: '#pragma unroll 4'
// left a runtime loop with dynamic mreg[q] indexing, demoting the M-row
// prefetch arrays to SCRATCH (77.8MB FETCH = spill traffic). Fix: FULL unroll
// of the q-loop + register copy so M stays in VGPRs (~150 regs, 1 wave/block).
// Everything else identical; absmax must stay exactly 0.04296875.
// P column map: [0,1024) q | [1024,3072) k | [3072,5120) v |
//   [5120,5152) beta-pre | [5152,5168) a-pre | [5168,6192) gate | pad
// ---------------------------------------------------------------------------

typedef unsigned short u16;
typedef __attribute__((ext_vector_type(8))) short bf16x8;
typedef __attribute__((ext_vector_type(4))) float f32x4;
typedef __attribute__((ext_vector_type(2))) float f32x2;
typedef __attribute__((ext_vector_type(4))) unsigned short u16x4;

#define TT 2048
#define NP 6208
#define NC 64
#define CS 64

__device__ __forceinline__ u16 f2bf(float f) {
  union { float f; uint32_t u; } v; v.f = f;
  uint32_t r = v.u + 0x7fffu + ((v.u >> 16) & 1u);  // RNE
  return (u16)(r >> 16);
}
__device__ __forceinline__ float bf2f(u16 b) {
  union { uint32_t u; float f; } v; v.u = ((uint32_t)b) << 16; return v.f;
}

__global__ void cvt_kernel(const float* __restrict__ src, u16* __restrict__ dst, long n) {
  long i = (long)blockIdx.x * 256 + threadIdx.x;
  if (i < n) dst[i] = f2bf(src[i]);
}

__global__ __launch_bounds__(256) void transT_kernel(const float* __restrict__ src,
    u16* __restrict__ dst, int rows, int cols) {
  __shared__ float tile[32][33];
  const int tx = threadIdx.x & 31, ty = threadIdx.x >> 5;
  const int c0 = blockIdx.x * 32, r0 = blockIdx.y * 32;
  for (int rr = ty; rr < 32; rr += 8)
    if (c0 + tx < cols) tile[rr][tx] = src[(size_t)(r0 + rr) * cols + c0 + tx];
  __syncthreads();
  for (int rr = ty; rr < 32; rr += 8)
    if (c0 + rr < cols) dst[(size_t)(c0 + rr) * rows + r0 + tx] = f2bf(tile[tx][rr]);
}

__global__ __launch_bounds__(256) void beacon_kernel(float* __restrict__ out, int n) {
  int i = blockIdx.x * 256 + threadIdx.x;
  if (i < n) out[i] = 4000.0f;
}

// C = A[M,K](bf16,lda) * BT[N,K]^T(bf16); out fp32 (Cf) or bf16 (Cb).
__global__ __launch_bounds__(64) void gemm_bt(const u16* __restrict__ A,
                                              const u16* __restrict__ BT,
                                              float* __restrict__ Cf,
                                              u16* __restrict__ Cb,
                                              int K, int lda, int ldc, int out_bf16) {
  const int bm = blockIdx.x * 64, bn = blockIdx.y * 64;
  const int lane = threadIdx.x;
  const int quad = lane >> 4, r = lane & 15;
  f32x4 acc[4][4] = {};
  const u16* ap = A  + (size_t)(bm + r) * lda + quad * 8;
  const u16* bp = BT + (size_t)(bn + r) * K   + quad * 8;
  for (int ks = 0; ks < K; ks += 32) {
    bf16x8 a[4], b[4];
#pragma unroll
    for (int i = 0; i < 4; i++)
      a[i] = *(const bf16x8*)(ap + (size_t)i * 16 * lda + ks);
#pragma unroll
    for (int j = 0; j < 4; j++)
      b[j] = *(const bf16x8*)(bp + (size_t)j * 16 * K + ks);
#pragma unroll
    for (int i = 0; i < 4; i++)
#pragma unroll
      for (int j = 0; j < 4; j++)
        acc[i][j] = __builtin_amdgcn_mfma_f32_16x16x32_bf16(a[i], b[j], acc[i][j], 0, 0, 0);
  }
#pragma unroll
  for (int i = 0; i < 4; i++)
#pragma unroll
    for (int j = 0; j < 4; j++)
#pragma unroll
      for (int rg = 0; rg < 4; rg++) {
        int row = bm + i * 16 + quad * 4 + rg;
        int col = bn + j * 16 + r;
        float v = acc[i][j][rg];
        if (out_bf16) Cb[(size_t)row * ldc + col] = f2bf(v);
        else          Cf[(size_t)row * ldc + col] = v;
      }
}

__global__ __launch_bounds__(64) void prep_kernel(float* __restrict__ P,
    const float* __restrict__ A_log, const float* __restrict__ dt_bias,
    float* __restrict__ betab, float* __restrict__ gbuf) {
  const int t = blockIdx.x >> 4, h = blockIdx.x & 15, lane = threadIdx.x;
  float* Pt = P + (size_t)t * NP;
  float qv = Pt[h * 64 + lane];
  float ss = qv * qv;
#pragma unroll
  for (int off = 32; off; off >>= 1) ss += __shfl_xor(ss, off);
  Pt[h * 64 + lane] = qv * rsqrtf(ss + 1e-6f) * 0.125f;
#pragma unroll
  for (int nh = 0; nh < 2; nh++) {
    float kv = Pt[1024 + nh * 1024 + h * 64 + lane];
    float ks = kv * kv;
#pragma unroll
    for (int off = 32; off; off >>= 1) ks += __shfl_xor(ks, off);
    Pt[1024 + nh * 1024 + h * 64 + lane] = kv * rsqrtf(ks + 1e-6f);
  }
  if (lane < 2) {
    float bb = Pt[5120 + lane * 16 + h];
    betab[(size_t)(2 * t + lane) * 16 + h] = 2.f / (1.f + expf(-bb));
  }
  if (lane == 0) {
    float a = Pt[5152 + h] + dt_bias[h];
    float sp = (a > 20.f) ? a : log1pf(expf(a));
    gbuf[t * 16 + h] = -expf(A_log[h]) * sp;
  }
}

// phase A: per (c,h): G, T, W(bf16), M(fp32,[m][mm]), Uv(bf16), NT(fp32,
// [d][m] transposed), cum. 4x4 register tiles, f32x4 LDS reads, unroll 4.
__global__ __launch_bounds__(256, 1) void phaseA_kernel(const float* __restrict__ P,
    const float* __restrict__ betab, const float* __restrict__ gbuf,
    u16* __restrict__ Wbuf, u16* __restrict__ Uvbuf,
    float* __restrict__ Mbuf, float* __restrict__ NTbuf, float* __restrict__ cumbuf) {
  const int c = blockIdx.x, h = blockIdx.y, tid = threadIdx.x;
  const int bi = tid >> 4, bj = tid & 15;
  __shared__ float kf[64][68];   // k rows [i][d]
  __shared__ float kT[64][68];   // [d][i]; later vf [j][d]
  __shared__ float Tt[64][68];   // Tt[j][i] = T[i][j]
  __shared__ float Sc[64][68];   // Ach -> Wl -> Uvl
  __shared__ float cumch[64], betach[64], bbch[64], rowfl[64];
  const size_t base = ((size_t)c * 16 + h) * 4096;

  for (int e = tid; e < 4096; e += 256) {
    int i = e >> 6, d = e & 63, s = c * 64 + i, t = s >> 1, nh = s & 1;
    float kv = P[(size_t)t * NP + 1024 + nh * 1024 + h * 64 + d];
    kf[i][d] = kv; kT[d][i] = kv;
  }
  if (tid < 64) betach[tid] = betab[(size_t)(c * 64 + tid) * 16 + h];
  __syncthreads();
  if (tid == 0) {
    float cum = 0.f;
    for (int i = 0; i < 64; i++) {
      if ((i & 1) == 0) cum += gbuf[(c * 32 + (i >> 1)) * 16 + h];
      cumch[i] = cum;
    }
  }
  __syncthreads();
  if (tid < 64) {
    bbch[tid] = betach[tid] * expf(cumch[tid]);
    rowfl[tid] = expf(cumch[63] - cumch[tid]);
  }
  // G[i][j] then scale -> Sc
  {
    float acc[4][4] = {};
#pragma unroll 4
    for (int d = 0; d < 64; d++) {
      f32x4 a = *(const f32x4*)&kT[d][4 * bi];
      f32x4 b = *(const f32x4*)&kT[d][4 * bj];
#pragma unroll
      for (int rr = 0; rr < 4; rr++)
#pragma unroll
        for (int cc = 0; cc < 4; cc++) acc[rr][cc] += a[rr] * b[cc];
    }
#pragma unroll
    for (int rr = 0; rr < 4; rr++)
#pragma unroll
      for (int cc = 0; cc < 4; cc++) {
        int i = 4 * bi + rr, j = 4 * bj + cc;
        Sc[i][j] = (j < i) ? betach[i] * expf(cumch[i] - cumch[j]) * acc[rr][cc] : 0.f;
      }
  }
  __syncthreads();
  // T = (I+A)^-1 forward substitution -> Tt[j][i]
  {
    int col = tid >> 2, part = tid & 3;
    if (part == 0) Tt[col][0] = (col == 0) ? 1.f : 0.f;
    for (int i = 1; i < 64; i++) {
      float partial = 0.f;
      for (int j = col + part; j < i; j += 4) partial += Sc[i][j] * Tt[col][j];
      partial += __shfl_xor(partial, 1);
      partial += __shfl_xor(partial, 2);
      if (part == 0) Tt[col][i] = ((i == col) ? 1.f : 0.f) - partial;
    }
  }
  __syncthreads();
  // stage v over kT region
  for (int e = tid; e < 4096; e += 256) {
    int i = e >> 6, d = e & 63, s = c * 64 + i, t = s >> 1, nh = s & 1;
    kT[i][d] = P[(size_t)t * NP + 3072 + nh * 1024 + h * 64 + d];
  }
  // W[i][d] = sum_j T[i][j]*bb[j]*k[j][d] -> Sc + Wbuf(bf16)
  {
    float acc[4][4] = {};
#pragma unroll 4
    for (int j = 0; j < 64; j++) {
      f32x4 tv = *(const f32x4*)&Tt[j][4 * bi];
      f32x4 kv = *(const f32x4*)&kf[j][4 * bj];
      float bbj = bbch[j];
#pragma unroll
      for (int rr = 0; rr < 4; rr++)
#pragma unroll
        for (int cc = 0; cc < 4; cc++) acc[rr][cc] += tv[rr] * bbj * kv[cc];
    }
#pragma unroll
    for (int rr = 0; rr < 4; rr++) {
      int i = 4 * bi + rr;
      u16x4 wb;
#pragma unroll
      for (int cc = 0; cc < 4; cc++) { Sc[i][4 * bj + cc] = acc[rr][cc]; wb[cc] = f2bf(acc[rr][cc]); }
      *(u16x4*)&Wbuf[base + (size_t)i * 64 + 4 * bj] = wb;
    }
  }
  __syncthreads();
  // M[m][mm] = bL*delta - sum_i rowf[i]*k[i][m]*W[i][mm]
  {
    const float bL = expf(cumch[63]);
    float acc[4][4] = {};
#pragma unroll 4
    for (int i = 0; i < 64; i++) {
      f32x4 kv = *(const f32x4*)&kf[i][4 * bi];
      f32x4 wv = *(const f32x4*)&Sc[i][4 * bj];
      float rf = rowfl[i];
#pragma unroll
      for (int rr = 0; rr < 4; rr++)
#pragma unroll
        for (int cc = 0; cc < 4; cc++) acc[rr][cc] += rf * kv[rr] * wv[cc];
    }
#pragma unroll
    for (int rr = 0; rr < 4; rr++) {
      int m = 4 * bi + rr;
      f32x4 mv;
#pragma unroll
      for (int cc = 0; cc < 4; cc++)
        mv[cc] = ((m == 4 * bj + cc) ? bL : 0.f) - acc[rr][cc];
      *(f32x4*)&Mbuf[base + (size_t)m * 64 + 4 * bj] = mv;
    }
  }
  __syncthreads();
  // Uv[i][d] = sum_j T[i][j]*beta[j]*v[j][d] -> Sc + Uvbuf(bf16)
  {
    float acc[4][4] = {};
#pragma unroll 4
    for (int j = 0; j < 64; j++) {
      f32x4 tv = *(const f32x4*)&Tt[j][4 * bi];
      f32x4 vv = *(const f32x4*)&kT[j][4 * bj];
      float be = betach[j];
#pragma unroll
      for (int rr = 0; rr < 4; rr++)
#pragma unroll
        for (int cc = 0; cc < 4; cc++) acc[rr][cc] += tv[rr] * be * vv[cc];
    }
#pragma unroll
    for (int rr = 0; rr < 4; rr++) {
      int i = 4 * bi + rr;
      u16x4 ub;
#pragma unroll
      for (int cc = 0; cc < 4; cc++) { Sc[i][4 * bj + cc] = acc[rr][cc]; ub[cc] = f2bf(acc[rr][cc]); }
      *(u16x4*)&Uvbuf[base + (size_t)i * 64 + 4 * bj] = ub;
    }
  }
  __syncthreads();
  // NT[d][m] = N[m][d] = sum_i rowf[i]*k[i][m]*Uv[i][d]   (transposed store)
  {
    float acc[4][4] = {};
#pragma unroll 4
    for (int i = 0; i < 64; i++) {
      f32x4 kv = *(const f32x4*)&kf[i][4 * bi];
      f32x4 uv = *(const f32x4*)&Sc[i][4 * bj];
      float rf = rowfl[i];
#pragma unroll
      for (int rr = 0; rr < 4; rr++)
#pragma unroll
        for (int cc = 0; cc < 4; cc++) acc[rr][cc] += rf * kv[rr] * uv[cc];
    }
#pragma unroll
    for (int cc = 0; cc < 4; cc++) {
      f32x4 nv;
#pragma unroll
      for (int rr = 0; rr < 4; rr++) nv[rr] = acc[rr][cc];   // m = 4bi+rr
      *(f32x4*)&NTbuf[base + (size_t)(4 * bj + cc) * 64 + 4 * bi] = nv;
    }
  }
  if (tid < 64) cumbuf[((size_t)c * 16 + h) * 64 + tid] = cumch[tid];
}

// phase B (column-parallel): S'[.,d] = M S[.,d] + N[.,d] per column.
// grid (32,16): colpair g, head h; 1 wave. Lane l = state row l, cols 2g,2g+1.
// M row held in 16 f32x4 REGISTERS (fully unrolled q loop — no dynamic
// indexing, no scratch). Column state in LDS ping-pong (broadcast reads).
__global__ __launch_bounds__(64) void phaseB_kernel(const float* __restrict__ Mbuf,
    const float* __restrict__ NTbuf, u16* __restrict__ S0Tbuf) {
  const int g = blockIdx.x, h = blockIdx.y, l = threadIdx.x;
  const int c0 = 2 * g, c1 = 2 * g + 1;
  __shared__ float Ssh[2][2][64];
  Ssh[0][0][l] = 0.f; Ssh[0][1][l] = 0.f;
  float s0 = 0.f, s1 = 0.f;
  f32x4 mreg[16];
  float n0, n1;
  {
    const float* Mc = Mbuf + (size_t)h * 4096 + (size_t)l * 64;
#pragma unroll
    for (int q = 0; q < 16; q++) mreg[q] = *(const f32x4*)(Mc + 4 * q);
    const float* Nc = NTbuf + (size_t)h * 4096;
    n0 = Nc[c0 * 64 + l]; n1 = Nc[c1 * 64 + l];
  }
  __syncthreads();
  int p = 0;
  for (int c = 0; c < NC; c++) {
    const size_t base = ((size_t)c * 16 + h) * 4096;
    // store incoming state (coalesced: 64 consecutive u16 per col)
    S0Tbuf[base + (size_t)c0 * 64 + l] = f2bf(s0);
    S0Tbuf[base + (size_t)c1 * 64 + l] = f2bf(s1);
    // prefetch next chunk (registers, fully unrolled)
    f32x4 mnext[16]; float nn0 = 0.f, nn1 = 0.f;
    if (c + 1 < NC) {
      const float* Mn = Mbuf + ((size_t)(c + 1) * 16 + h) * 4096 + (size_t)l * 64;
#pragma unroll
      for (int q = 0; q < 16; q++) mnext[q] = *(const f32x4*)(Mn + 4 * q);
      const float* Nn = NTbuf + ((size_t)(c + 1) * 16 + h) * 4096;
      nn0 = Nn[c0 * 64 + l]; nn1 = Nn[c1 * 64 + l];
    }
    float acc0 = n0, acc1 = n1;
#pragma unroll
    for (int q = 0; q < 16; q++) {       // FULL unroll: mreg stays in VGPRs
      f32x4 mv = mreg[q];
      f32x4 sv0 = *(const f32x4*)&Ssh[p][0][4 * q];   // broadcast
      f32x4 sv1 = *(const f32x4*)&Ssh[p][1][4 * q];
#pragma unroll
      for (int t = 0; t < 4; t++) { acc0 += mv[t] * sv0[t]; acc1 += mv[t] * sv1[t]; }
    }
    s0 = acc0; s1 = acc1;
    Ssh[p ^ 1][0][l] = s0; Ssh[p ^ 1][1][l] = s1;
    __syncthreads();
    p ^= 1;
#pragma unroll
    for (int q = 0; q < 16; q++) mreg[q] = mnext[q];
    n0 = nn0; n1 = nn1;
  }
}

// phase B2: U = Uv - W*S0 (register-blocked; S0 staged transposed from S0T)
__global__ __launch_bounds__(256) void phaseB2_kernel(const u16* __restrict__ Wbuf,
    const u16* __restrict__ S0Tbuf, u16* __restrict__ Uvbuf) {
  const int c = blockIdx.x, h = blockIdx.y, tid = threadIdx.x;
  const int bi = tid >> 4, bd = tid & 15;
  __shared__ float WTl[64][68], S0l[64][68];
  const size_t base = ((size_t)c * 16 + h) * 4096;
  for (int e = tid; e < 4096; e += 256) {
    int i = e >> 6, m = e & 63;
    WTl[m][i] = bf2f(Wbuf[base + e]);          // W [i][m] -> WTl[m][i]
    S0l[m][i] = bf2f(S0Tbuf[base + e]);        // S0T [d][m] -> S0l[m][d]
  }
  __syncthreads();
  float acc[4][4] = {};
#pragma unroll 4
  for (int m = 0; m < 64; m++) {
    f32x4 wv = *(const f32x4*)&WTl[m][4 * bi];
    f32x4 sv = *(const f32x4*)&S0l[m][4 * bd];
#pragma unroll
    for (int rr = 0; rr < 4; rr++)
#pragma unroll
      for (int cc = 0; cc < 4; cc++) acc[rr][cc] += wv[rr] * sv[cc];
  }
#pragma unroll
  for (int rr = 0; rr < 4; rr++) {
    int i = 4 * bi + rr;
    u16x4 uv = *(const u16x4*)&Uvbuf[base + (size_t)i * 64 + 4 * bd];
    u16x4 ob;
#pragma unroll
    for (int cc = 0; cc < 4; cc++) ob[cc] = f2bf(bf2f(uv[cc]) - acc[rr][cc]);
    *(u16x4*)&Uvbuf[base + (size_t)i * 64 + 4 * bd] = ob;
  }
}

// phase C: o = e^cum q.S0 + tril(decay qk^T) U, RMSNorm+swish -> ybuf
__global__ __launch_bounds__(256) void phaseC_kernel(const float* __restrict__ P,
    const float* __restrict__ cumbuf, const u16* __restrict__ Ubuf,
    const u16* __restrict__ S0Tbuf, const float* __restrict__ nw,
    u16* __restrict__ ybuf) {
  const int c = blockIdx.x, h = blockIdx.y, tid = threadIdx.x;
  const int rb = tid >> 4, jb = tid & 15;
  __shared__ float qT[64][36];    // [d][r]; reused as ol[32][68]
  __shared__ float kTc[64][68];   // [d][j]; reused as S0l[m][d]
  __shared__ float Ul[64][68];
  __shared__ float PmT[64][36];
  __shared__ float cuml[64], nwl[64];
  const size_t base = (size_t)c * 16 + h;
  for (int e = tid; e < 2048; e += 256) {
    int r = e >> 6, d = e & 63;
    qT[d][r] = P[(size_t)(c * 32 + r) * NP + h * 64 + d];
  }
  for (int e = tid; e < 4096; e += 256) {
    int j = e >> 6, d = e & 63, s = c * 64 + j, t = s >> 1, nh = s & 1;
    kTc[d][j] = P[(size_t)t * NP + 1024 + nh * 1024 + h * 64 + d];
    Ul[j][d] = bf2f(Ubuf[base * 4096 + e]);
  }
  if (tid < 64) { cuml[tid] = cumbuf[base * 64 + tid]; nwl[tid] = nw[tid]; }
  __syncthreads();
  {
    float pa[2][4] = {};
#pragma unroll 4
    for (int d = 0; d < 64; d++) {
      f32x2 qv = *(const f32x2*)&qT[d][2 * rb];
      f32x4 kv = *(const f32x4*)&kTc[d][4 * jb];
#pragma unroll
      for (int rr = 0; rr < 2; rr++)
#pragma unroll
        for (int cc = 0; cc < 4; cc++) pa[rr][cc] += qv[rr] * kv[cc];
    }
#pragma unroll
    for (int rr = 0; rr < 2; rr++)
#pragma unroll
      for (int cc = 0; cc < 4; cc++) {
        int r = 2 * rb + rr, i = 2 * r + 1, j = 4 * jb + cc;
        PmT[j][r] = (j <= i) ? expf(cuml[i] - cuml[j]) * pa[rr][cc] : 0.f;
      }
  }
  __syncthreads();
  for (int e = tid; e < 4096; e += 256) {    // S0T [d][m] -> kTc[m][d]
    int d = e >> 6, m = e & 63;
    kTc[m][d] = bf2f(S0Tbuf[base * 4096 + e]);
  }
  __syncthreads();
  float o[2][4];
  {
    float a1[2][4] = {}, a2[2][4] = {};
#pragma unroll 4
    for (int m = 0; m < 64; m++) {
      f32x2 qv = *(const f32x2*)&qT[m][2 * rb];
      f32x4 sv = *(const f32x4*)&kTc[m][4 * jb];
#pragma unroll
      for (int rr = 0; rr < 2; rr++)
#pragma unroll
        for (int cc = 0; cc < 4; cc++) a1[rr][cc] += qv[rr] * sv[cc];
    }
#pragma unroll 4
    for (int j = 0; j < 64; j++) {
      f32x2 pv = *(const f32x2*)&PmT[j][2 * rb];
      f32x4 uv = *(const f32x4*)&Ul[j][4 * jb];
#pragma unroll
      for (int rr = 0; rr < 2; rr++)
#pragma unroll
        for (int cc = 0; cc < 4; cc++) a2[rr][cc] += pv[rr] * uv[cc];
    }
#pragma unroll
    for (int rr = 0; rr < 2; rr++) {
      float ec = expf(cuml[2 * (2 * rb + rr) + 1]);
#pragma unroll
      for (int cc = 0; cc < 4; cc++) o[rr][cc] = a1[rr][cc] * ec + a2[rr][cc];
    }
  }
  __syncthreads();
  float* ol = &qT[0][0];   // [32][68]
#pragma unroll
  for (int rr = 0; rr < 2; rr++)
#pragma unroll
    for (int cc = 0; cc < 4; cc++)
      ol[(2 * rb + rr) * 68 + 4 * jb + cc] = o[rr][cc];
  __syncthreads();
  for (int e = tid; e < 2048; e += 256) {
    int r = e >> 6, d = e & 63;
    float ov = ol[r * 68 + d];
    float ss = ov * ov;
#pragma unroll
    for (int off = 32; off; off >>= 1) ss += __shfl_xor(ss, off);
    float on = ov * rsqrtf(ss * (1.f / 64.f) + 1e-5f) * nwl[d];
    int t = c * 32 + r;
    float gt = P[(size_t)t * NP + 5168 + h * 64 + d];
    float sw = gt / (1.f + expf(-gt));
    ybuf[(size_t)t * 1024 + h * 64 + d] = f2bf(on * sw);
  }
}

extern "C" void kernel_launch(void* const* d_in, const int* in_sizes, int n_in,
                              void* d_out, int out_size, void* d_ws, size_t ws_size,
                              hipStream_t stream) {
  const float* x       = (const float*)d_in[0];
  const float* Wq      = (const float*)d_in[1];
  const float* Wk      = (const float*)d_in[2];
  const float* Wv      = (const float*)d_in[3];
  const float* Wb      = (const float*)d_in[4];
  const float* Wa      = (const float*)d_in[5];
  const float* A_log   = (const float*)d_in[6];
  const float* dt_bias = (const float*)d_in[7];
  const float* Wg      = (const float*)d_in[8];
  const float* nw      = (const float*)d_in[9];
  const float* Wo      = (const float*)d_in[10];
  float* out = (float*)d_out;

  char* w = (char*)d_ws;
  size_t used = 0;
  auto alloc = [&](size_t bytes) {
    char* p = w + used; used += (bytes + 255) & ~(size_t)255; return p;
  };
  u16*   xb    = (u16*)  alloc(2048UL * 1024 * 2);
  u16*   WT    = (u16*)  alloc((size_t)NP * 1024 * 2);
  u16*   WoT   = (u16*)  alloc(1024UL * 1024 * 2);
  float* P     = (float*)alloc(2048UL * NP * 4);
  float* betab = (float*)alloc(4096UL * 16 * 4);
  float* gbuf  = (float*)alloc(2048UL * 16 * 4);
  u16*   ybuf  = (u16*)  alloc(2048UL * 1024 * 2);
  u16*   Wbuf  = (u16*)  alloc((size_t)NC * 16 * 4096 * 2);
  u16*   Uvbuf = (u16*)  alloc((size_t)NC * 16 * 4096 * 2);
  u16*   S0Tb  = (u16*)  alloc((size_t)NC * 16 * 4096 * 2);
  float* Mbuf  = (float*)alloc((size_t)NC * 16 * 4096 * 4);
  float* NTbuf = (float*)alloc((size_t)NC * 16 * 4096 * 4);
  float* cumb  = (float*)alloc((size_t)NC * 16 * 64 * 4);

  auto tgrid = [](long n) { return dim3((unsigned)((n + 255) / 256)); };
  if (used > ws_size) {
    beacon_kernel<<<tgrid(out_size), 256, 0, stream>>>(out, out_size);
    return;
  }

  hipMemsetAsync(WT + 6192UL * 1024, 0, 16UL * 1024 * 2, stream);

  cvt_kernel<<<tgrid(2048L*1024), 256, 0, stream>>>(x, xb, 2048L * 1024);
  auto trgrid = [](int cols) { return dim3((unsigned)((cols + 31) / 32), 32); };
  transT_kernel<<<trgrid(1024), 256, 0, stream>>>(Wq, WT + 0L,         1024, 1024);
  transT_kernel<<<trgrid(2048), 256, 0, stream>>>(Wk, WT + 1024L*1024, 1024, 2048);
  transT_kernel<<<trgrid(2048), 256, 0, stream>>>(Wv, WT + 3072L*1024, 1024, 2048);
  transT_kernel<<<trgrid(32),   256, 0, stream>>>(Wb, WT + 5120L*1024, 1024, 32);
  transT_kernel<<<trgrid(16),   256, 0, stream>>>(Wa, WT + 5152L*1024, 1024, 16);
  transT_kernel<<<trgrid(1024), 256, 0, stream>>>(Wg, WT + 5168L*1024, 1024, 1024);
  transT_kernel<<<trgrid(1024), 256, 0, stream>>>(Wo, WoT,             1024, 1024);

  gemm_bt<<<dim3(32, 97), 64, 0, stream>>>(xb, WT, P, nullptr, 1024, 1024, NP, 0);
  prep_kernel<<<dim3(2048 * 16), 64, 0, stream>>>(P, A_log, dt_bias, betab, gbuf);

  phaseA_kernel<<<dim3(NC, 16), 256, 0, stream>>>(P, betab, gbuf, Wbuf, Uvbuf, Mbuf, NTbuf, cumb);
  phaseB_kernel<<<dim3(32, 16), 64, 0, stream>>>(Mbuf, NTbuf, S0Tb);
  phaseB2_kernel<<<dim3(NC, 16), 256, 0, stream>>>(Wbuf, S0Tb, Uvbuf);
  phaseC_kernel<<<dim3(NC, 16), 256, 0, stream>>>(P, cumb, Uvbuf, S0Tb, nw, ybuf);

  gemm_bt<<<dim3(32, 16), 64, 0, stream>>>(ybuf, WoT, out, nullptr, 1024, 1024, 1024, 0);
}

// Round 12
// 449.041 us; speedup vs baseline: 2.8746x; 1.0959x over previous
//
#include <hip/hip_runtime.h>
#include <stdint.h>

// ---------------------------------------------------------------------------
// DeltaNet (gated delta rule) forward, MI355X gfx950. Round 12.
// Round 11: 492us. Changes (all bit-exact -> absmax stays 0.04296875):
//  1) gemm128: 128x128 tile, 4 waves, LDS staging (pad-40 rows: a-frag b128
//     reads 2-way max). Same per-output mfma K-order as before -> identical.
//     WT padded to 6272 zero rows for the N=6208 edge.
//  2) phaseA W/Uv j-loops cut to j<4bi+4 (T lower-tri; dropped terms exact 0);
//     phaseC U-path j-loop cut to j<4rb+4 (Pm zero above diag).
//  3) 7 transpose launches fused into one segmented kernel.
// P column map: [0,1024) q | [1024,3072) k | [3072,5120) v |
//   [5120,5152) beta-pre | [5152,5168) a-pre | [5168,6192) gate | pad
// ---------------------------------------------------------------------------

typedef unsigned short u16;
typedef __attribute__((ext_vector_type(8))) short bf16x8;
typedef __attribute__((ext_vector_type(4))) float f32x4;
typedef __attribute__((ext_vector_type(2))) float f32x2;
typedef __attribute__((ext_vector_type(4))) unsigned short u16x4;

#define TT 2048
#define NP 6208
#define NC 64
#define CS 64

__device__ __forceinline__ u16 f2bf(float f) {
  union { float f; uint32_t u; } v; v.f = f;
  uint32_t r = v.u + 0x7fffu + ((v.u >> 16) & 1u);  // RNE
  return (u16)(r >> 16);
}
__device__ __forceinline__ float bf2f(u16 b) {
  union { uint32_t u; float f; } v; v.u = ((uint32_t)b) << 16; return v.f;
}

__global__ void cvt_kernel(const float* __restrict__ src, u16* __restrict__ dst, long n) {
  long i = (long)blockIdx.x * 256 + threadIdx.x;
  if (i < n) dst[i] = f2bf(src[i]);
}

// fused transpose+convert of all 7 weight matrices (rows always 1024)
__global__ __launch_bounds__(256) void transAll_kernel(
    const float* __restrict__ Wq, const float* __restrict__ Wk,
    const float* __restrict__ Wv, const float* __restrict__ Wb,
    const float* __restrict__ Wa, const float* __restrict__ Wg,
    const float* __restrict__ Wo, u16* __restrict__ WT, u16* __restrict__ WoT) {
  int bx = blockIdx.x;
  const float* src; u16* dst; int cols;
  if      (bx < 32)  { src = Wq; dst = WT;                cols = 1024; }
  else if (bx < 96)  { src = Wk; dst = WT + 1024UL*1024;  cols = 2048; bx -= 32; }
  else if (bx < 160) { src = Wv; dst = WT + 3072UL*1024;  cols = 2048; bx -= 96; }
  else if (bx < 161) { src = Wb; dst = WT + 5120UL*1024;  cols = 32;   bx -= 160; }
  else if (bx < 162) { src = Wa; dst = WT + 5152UL*1024;  cols = 16;   bx -= 161; }
  else if (bx < 194) { src = Wg; dst = WT + 5168UL*1024;  cols = 1024; bx -= 162; }
  else               { src = Wo; dst = WoT;               cols = 1024; bx -= 194; }
  __shared__ float tile[32][33];
  const int tx = threadIdx.x & 31, ty = threadIdx.x >> 5;
  const int c0 = bx * 32, r0 = blockIdx.y * 32;
  for (int rr = ty; rr < 32; rr += 8)
    if (c0 + tx < cols) tile[rr][tx] = src[(size_t)(r0 + rr) * cols + c0 + tx];
  __syncthreads();
  for (int rr = ty; rr < 32; rr += 8)
    if (c0 + rr < cols) dst[(size_t)(c0 + rr) * 1024 + r0 + tx] = f2bf(tile[tx][rr]);
}

__global__ __launch_bounds__(256) void beacon_kernel(float* __restrict__ out, int n) {
  int i = blockIdx.x * 256 + threadIdx.x;
  if (i < n) out[i] = 4000.0f;
}

// 128x128-tile GEMM: C = A[M,K](bf16,lda) * BT[N,K]^T(bf16, row stride K).
// 4 waves, each a 64x64 quadrant. BT must be zero-padded to grid.y*128 rows.
// Per-output mfma K-order identical to the old 64-tile kernel (bit-exact).
__global__ __launch_bounds__(256) void gemm128(const u16* __restrict__ A,
    const u16* __restrict__ BT, float* __restrict__ Cf, u16* __restrict__ Cb,
    int K, int lda, int ldc, int Nmax, int out_bf16) {
  const int bm = blockIdx.x * 128, bn = blockIdx.y * 128;
  const int tid = threadIdx.x, w = tid >> 6, lane = tid & 63;
  const int wr = (w >> 1) * 64, wc = (w & 1) * 64;
  const int quad = lane >> 4, r = lane & 15;
  __shared__ u16 As[128][40], Bs[128][40];   // pad 32->40: frag reads 2-way max
  f32x4 acc[4][4] = {};
  const int srow = tid >> 1, scg = (tid & 1) * 16;   // stage: 16 els/thread
  for (int ks = 0; ks < K; ks += 32) {
    bf16x8 a0 = *(const bf16x8*)(A  + (size_t)(bm + srow) * lda + ks + scg);
    bf16x8 a1 = *(const bf16x8*)(A  + (size_t)(bm + srow) * lda + ks + scg + 8);
    bf16x8 b0 = *(const bf16x8*)(BT + (size_t)(bn + srow) * K   + ks + scg);
    bf16x8 b1 = *(const bf16x8*)(BT + (size_t)(bn + srow) * K   + ks + scg + 8);
    __syncthreads();   // prev-iter readers done
    *(bf16x8*)&As[srow][scg]     = a0;
    *(bf16x8*)&As[srow][scg + 8] = a1;
    *(bf16x8*)&Bs[srow][scg]     = b0;
    *(bf16x8*)&Bs[srow][scg + 8] = b1;
    __syncthreads();
    bf16x8 af[4], bf[4];
#pragma unroll
    for (int i = 0; i < 4; i++) af[i] = *(const bf16x8*)&As[wr + i * 16 + r][quad * 8];
#pragma unroll
    for (int j = 0; j < 4; j++) bf[j] = *(const bf16x8*)&Bs[wc + j * 16 + r][quad * 8];
#pragma unroll
    for (int i = 0; i < 4; i++)
#pragma unroll
      for (int j = 0; j < 4; j++)
        acc[i][j] = __builtin_amdgcn_mfma_f32_16x16x32_bf16(af[i], bf[j], acc[i][j], 0, 0, 0);
  }
#pragma unroll
  for (int i = 0; i < 4; i++)
#pragma unroll
    for (int j = 0; j < 4; j++)
#pragma unroll
      for (int rg = 0; rg < 4; rg++) {
        int row = bm + wr + i * 16 + quad * 4 + rg;
        int col = bn + wc + j * 16 + r;
        if (col < Nmax) {
          float v = acc[i][j][rg];
          if (out_bf16) Cb[(size_t)row * ldc + col] = f2bf(v);
          else          Cf[(size_t)row * ldc + col] = v;
        }
      }
}

__global__ __launch_bounds__(64) void prep_kernel(float* __restrict__ P,
    const float* __restrict__ A_log, const float* __restrict__ dt_bias,
    float* __restrict__ betab, float* __restrict__ gbuf) {
  const int t = blockIdx.x >> 4, h = blockIdx.x & 15, lane = threadIdx.x;
  float* Pt = P + (size_t)t * NP;
  float qv = Pt[h * 64 + lane];
  float ss = qv * qv;
#pragma unroll
  for (int off = 32; off; off >>= 1) ss += __shfl_xor(ss, off);
  Pt[h * 64 + lane] = qv * rsqrtf(ss + 1e-6f) * 0.125f;
#pragma unroll
  for (int nh = 0; nh < 2; nh++) {
    float kv = Pt[1024 + nh * 1024 + h * 64 + lane];
    float ks = kv * kv;
#pragma unroll
    for (int off = 32; off; off >>= 1) ks += __shfl_xor(ks, off);
    Pt[1024 + nh * 1024 + h * 64 + lane] = kv * rsqrtf(ks + 1e-6f);
  }
  if (lane < 2) {
    float bb = Pt[5120 + lane * 16 + h];
    betab[(size_t)(2 * t + lane) * 16 + h] = 2.f / (1.f + expf(-bb));
  }
  if (lane == 0) {
    float a = Pt[5152 + h] + dt_bias[h];
    float sp = (a > 20.f) ? a : log1pf(expf(a));
    gbuf[t * 16 + h] = -expf(A_log[h]) * sp;
  }
}

// phase A: per (c,h): G, T, W(bf16), M(fp32), Uv(bf16), NT(fp32), cum.
// W/Uv j-loops triangular (j<4bi+4) — dropped terms are exact zeros.
__global__ __launch_bounds__(256, 1) void phaseA_kernel(const float* __restrict__ P,
    const float* __restrict__ betab, const float* __restrict__ gbuf,
    u16* __restrict__ Wbuf, u16* __restrict__ Uvbuf,
    float* __restrict__ Mbuf, float* __restrict__ NTbuf, float* __restrict__ cumbuf) {
  const int c = blockIdx.x, h = blockIdx.y, tid = threadIdx.x;
  const int bi = tid >> 4, bj = tid & 15;
  __shared__ float kf[64][68];
  __shared__ float kT[64][68];   // later vf
  __shared__ float Tt[64][68];
  __shared__ float Sc[64][68];
  __shared__ float cumch[64], betach[64], bbch[64], rowfl[64];
  const size_t base = ((size_t)c * 16 + h) * 4096;

  for (int e = tid; e < 4096; e += 256) {
    int i = e >> 6, d = e & 63, s = c * 64 + i, t = s >> 1, nh = s & 1;
    float kv = P[(size_t)t * NP + 1024 + nh * 1024 + h * 64 + d];
    kf[i][d] = kv; kT[d][i] = kv;
  }
  if (tid < 64) betach[tid] = betab[(size_t)(c * 64 + tid) * 16 + h];
  __syncthreads();
  if (tid == 0) {
    float cum = 0.f;
    for (int i = 0; i < 64; i++) {
      if ((i & 1) == 0) cum += gbuf[(c * 32 + (i >> 1)) * 16 + h];
      cumch[i] = cum;
    }
  }
  __syncthreads();
  if (tid < 64) {
    bbch[tid] = betach[tid] * expf(cumch[tid]);
    rowfl[tid] = expf(cumch[63] - cumch[tid]);
  }
  // G then scale -> Sc
  {
    float acc[4][4] = {};
#pragma unroll 4
    for (int d = 0; d < 64; d++) {
      f32x4 a = *(const f32x4*)&kT[d][4 * bi];
      f32x4 b = *(const f32x4*)&kT[d][4 * bj];
#pragma unroll
      for (int rr = 0; rr < 4; rr++)
#pragma unroll
        for (int cc = 0; cc < 4; cc++) acc[rr][cc] += a[rr] * b[cc];
    }
#pragma unroll
    for (int rr = 0; rr < 4; rr++)
#pragma unroll
      for (int cc = 0; cc < 4; cc++) {
        int i = 4 * bi + rr, j = 4 * bj + cc;
        Sc[i][j] = (j < i) ? betach[i] * expf(cumch[i] - cumch[j]) * acc[rr][cc] : 0.f;
      }
  }
  __syncthreads();
  // T = (I+A)^-1 forward substitution -> Tt[j][i]
  {
    int col = tid >> 2, part = tid & 3;
    if (part == 0) Tt[col][0] = (col == 0) ? 1.f : 0.f;
    for (int i = 1; i < 64; i++) {
      float partial = 0.f;
      for (int j = col + part; j < i; j += 4) partial += Sc[i][j] * Tt[col][j];
      partial += __shfl_xor(partial, 1);
      partial += __shfl_xor(partial, 2);
      if (part == 0) Tt[col][i] = ((i == col) ? 1.f : 0.f) - partial;
    }
  }
  __syncthreads();
  // stage v over kT
  for (int e = tid; e < 4096; e += 256) {
    int i = e >> 6, d = e & 63, s = c * 64 + i, t = s >> 1, nh = s & 1;
    kT[i][d] = P[(size_t)t * NP + 3072 + nh * 1024 + h * 64 + d];
  }
  // W[i][d] = sum_{j<=i} T[i][j]*bb[j]*k[j][d]  (triangular trip)
  {
    float acc[4][4] = {};
#pragma unroll 4
    for (int j = 0; j < 4 * bi + 4; j++) {
      f32x4 tv = *(const f32x4*)&Tt[j][4 * bi];
      f32x4 kv = *(const f32x4*)&kf[j][4 * bj];
      float bbj = bbch[j];
#pragma unroll
      for (int rr = 0; rr < 4; rr++)
#pragma unroll
        for (int cc = 0; cc < 4; cc++) acc[rr][cc] += tv[rr] * bbj * kv[cc];
    }
#pragma unroll
    for (int rr = 0; rr < 4; rr++) {
      int i = 4 * bi + rr;
      u16x4 wb;
#pragma unroll
      for (int cc = 0; cc < 4; cc++) { Sc[i][4 * bj + cc] = acc[rr][cc]; wb[cc] = f2bf(acc[rr][cc]); }
      *(u16x4*)&Wbuf[base + (size_t)i * 64 + 4 * bj] = wb;
    }
  }
  __syncthreads();
  // M[m][mm] = bL*delta - sum_i rowf[i]*k[i][m]*W[i][mm]
  {
    const float bL = expf(cumch[63]);
    float acc[4][4] = {};
#pragma unroll 4
    for (int i = 0; i < 64; i++) {
      f32x4 kv = *(const f32x4*)&kf[i][4 * bi];
      f32x4 wv = *(const f32x4*)&Sc[i][4 * bj];
      float rf = rowfl[i];
#pragma unroll
      for (int rr = 0; rr < 4; rr++)
#pragma unroll
        for (int cc = 0; cc < 4; cc++) acc[rr][cc] += rf * kv[rr] * wv[cc];
    }
#pragma unroll
    for (int rr = 0; rr < 4; rr++) {
      int m = 4 * bi + rr;
      f32x4 mv;
#pragma unroll
      for (int cc = 0; cc < 4; cc++)
        mv[cc] = ((m == 4 * bj + cc) ? bL : 0.f) - acc[rr][cc];
      *(f32x4*)&Mbuf[base + (size_t)m * 64 + 4 * bj] = mv;
    }
  }
  __syncthreads();
  // Uv[i][d] = sum_{j<=i} T[i][j]*beta[j]*v[j][d]  (triangular trip)
  {
    float acc[4][4] = {};
#pragma unroll 4
    for (int j = 0; j < 4 * bi + 4; j++) {
      f32x4 tv = *(const f32x4*)&Tt[j][4 * bi];
      f32x4 vv = *(const f32x4*)&kT[j][4 * bj];
      float be = betach[j];
#pragma unroll
      for (int rr = 0; rr < 4; rr++)
#pragma unroll
        for (int cc = 0; cc < 4; cc++) acc[rr][cc] += tv[rr] * be * vv[cc];
    }
#pragma unroll
    for (int rr = 0; rr < 4; rr++) {
      int i = 4 * bi + rr;
      u16x4 ub;
#pragma unroll
      for (int cc = 0; cc < 4; cc++) { Sc[i][4 * bj + cc] = acc[rr][cc]; ub[cc] = f2bf(acc[rr][cc]); }
      *(u16x4*)&Uvbuf[base + (size_t)i * 64 + 4 * bj] = ub;
    }
  }
  __syncthreads();
  // NT[d][m] = sum_i rowf[i]*k[i][m]*Uv[i][d]
  {
    float acc[4][4] = {};
#pragma unroll 4
    for (int i = 0; i < 64; i++) {
      f32x4 kv = *(const f32x4*)&kf[i][4 * bi];
      f32x4 uv = *(const f32x4*)&Sc[i][4 * bj];
      float rf = rowfl[i];
#pragma unroll
      for (int rr = 0; rr < 4; rr++)
#pragma unroll
        for (int cc = 0; cc < 4; cc++) acc[rr][cc] += rf * kv[rr] * uv[cc];
    }
#pragma unroll
    for (int cc = 0; cc < 4; cc++) {
      f32x4 nv;
#pragma unroll
      for (int rr = 0; rr < 4; rr++) nv[rr] = acc[rr][cc];
      *(f32x4*)&NTbuf[base + (size_t)(4 * bj + cc) * 64 + 4 * bi] = nv;
    }
  }
  if (tid < 64) cumbuf[((size_t)c * 16 + h) * 64 + tid] = cumch[tid];
}

// phase B (column-parallel, M in registers, full unroll)
__global__ __launch_bounds__(64) void phaseB_kernel(const float* __restrict__ Mbuf,
    const float* __restrict__ NTbuf, u16* __restrict__ S0Tbuf) {
  const int g = blockIdx.x, h = blockIdx.y, l = threadIdx.x;
  const int c0 = 2 * g, c1 = 2 * g + 1;
  __shared__ float Ssh[2][2][64];
  Ssh[0][0][l] = 0.f; Ssh[0][1][l] = 0.f;
  float s0 = 0.f, s1 = 0.f;
  f32x4 mreg[16];
  float n0, n1;
  {
    const float* Mc = Mbuf + (size_t)h * 4096 + (size_t)l * 64;
#pragma unroll
    for (int q = 0; q < 16; q++) mreg[q] = *(const f32x4*)(Mc + 4 * q);
    const float* Nc = NTbuf + (size_t)h * 4096;
    n0 = Nc[c0 * 64 + l]; n1 = Nc[c1 * 64 + l];
  }
  __syncthreads();
  int p = 0;
  for (int c = 0; c < NC; c++) {
    const size_t base = ((size_t)c * 16 + h) * 4096;
    S0Tbuf[base + (size_t)c0 * 64 + l] = f2bf(s0);
    S0Tbuf[base + (size_t)c1 * 64 + l] = f2bf(s1);
    f32x4 mnext[16]; float nn0 = 0.f, nn1 = 0.f;
    if (c + 1 < NC) {
      const float* Mn = Mbuf + ((size_t)(c + 1) * 16 + h) * 4096 + (size_t)l * 64;
#pragma unroll
      for (int q = 0; q < 16; q++) mnext[q] = *(const f32x4*)(Mn + 4 * q);
      const float* Nn = NTbuf + ((size_t)(c + 1) * 16 + h) * 4096;
      nn0 = Nn[c0 * 64 + l]; nn1 = Nn[c1 * 64 + l];
    }
    float acc0 = n0, acc1 = n1;
#pragma unroll
    for (int q = 0; q < 16; q++) {
      f32x4 mv = mreg[q];
      f32x4 sv0 = *(const f32x4*)&Ssh[p][0][4 * q];
      f32x4 sv1 = *(const f32x4*)&Ssh[p][1][4 * q];
#pragma unroll
      for (int t = 0; t < 4; t++) { acc0 += mv[t] * sv0[t]; acc1 += mv[t] * sv1[t]; }
    }
    s0 = acc0; s1 = acc1;
    Ssh[p ^ 1][0][l] = s0; Ssh[p ^ 1][1][l] = s1;
    __syncthreads();
    p ^= 1;
#pragma unroll
    for (int q = 0; q < 16; q++) mreg[q] = mnext[q];
    n0 = nn0; n1 = nn1;
  }
}

// phase B2: U = Uv - W*S0
__global__ __launch_bounds__(256) void phaseB2_kernel(const u16* __restrict__ Wbuf,
    const u16* __restrict__ S0Tbuf, u16* __restrict__ Uvbuf) {
  const int c = blockIdx.x, h = blockIdx.y, tid = threadIdx.x;
  const int bi = tid >> 4, bd = tid & 15;
  __shared__ float WTl[64][68], S0l[64][68];
  const size_t base = ((size_t)c * 16 + h) * 4096;
  for (int e = tid; e < 4096; e += 256) {
    int i = e >> 6, m = e & 63;
    WTl[m][i] = bf2f(Wbuf[base + e]);
    S0l[m][i] = bf2f(S0Tbuf[base + e]);
  }
  __syncthreads();
  float acc[4][4] = {};
#pragma unroll 4
  for (int m = 0; m < 64; m++) {
    f32x4 wv = *(const f32x4*)&WTl[m][4 * bi];
    f32x4 sv = *(const f32x4*)&S0l[m][4 * bd];
#pragma unroll
    for (int rr = 0; rr < 4; rr++)
#pragma unroll
      for (int cc = 0; cc < 4; cc++) acc[rr][cc] += wv[rr] * sv[cc];
  }
#pragma unroll
  for (int rr = 0; rr < 4; rr++) {
    int i = 4 * bi + rr;
    u16x4 uv = *(const u16x4*)&Uvbuf[base + (size_t)i * 64 + 4 * bd];
    u16x4 ob;
#pragma unroll
    for (int cc = 0; cc < 4; cc++) ob[cc] = f2bf(bf2f(uv[cc]) - acc[rr][cc]);
    *(u16x4*)&Uvbuf[base + (size_t)i * 64 + 4 * bd] = ob;
  }
}

// phase C: o = e^cum q.S0 + tril(decay qk^T) U, RMSNorm+swish -> ybuf
__global__ __launch_bounds__(256) void phaseC_kernel(const float* __restrict__ P,
    const float* __restrict__ cumbuf, const u16* __restrict__ Ubuf,
    const u16* __restrict__ S0Tbuf, const float* __restrict__ nw,
    u16* __restrict__ ybuf) {
  const int c = blockIdx.x, h = blockIdx.y, tid = threadIdx.x;
  const int rb = tid >> 4, jb = tid & 15;
  __shared__ float qT[64][36];    // [d][r]; reused as ol[32][68]
  __shared__ float kTc[64][68];   // [d][j]; reused as S0l[m][d]
  __shared__ float Ul[64][68];
  __shared__ float PmT[64][36];
  __shared__ float cuml[64], nwl[64];
  const size_t base = (size_t)c * 16 + h;
  for (int e = tid; e < 2048; e += 256) {
    int r = e >> 6, d = e & 63;
    qT[d][r] = P[(size_t)(c * 32 + r) * NP + h * 64 + d];
  }
  for (int e = tid; e < 4096; e += 256) {
    int j = e >> 6, d = e & 63, s = c * 64 + j, t = s >> 1, nh = s & 1;
    kTc[d][j] = P[(size_t)t * NP + 1024 + nh * 1024 + h * 64 + d];
    Ul[j][d] = bf2f(Ubuf[base * 4096 + e]);
  }
  if (tid < 64) { cuml[tid] = cumbuf[base * 64 + tid]; nwl[tid] = nw[tid]; }
  __syncthreads();
  {
    float pa[2][4] = {};
#pragma unroll 4
    for (int d = 0; d < 64; d++) {
      f32x2 qv = *(const f32x2*)&qT[d][2 * rb];
      f32x4 kv = *(const f32x4*)&kTc[d][4 * jb];
#pragma unroll
      for (int rr = 0; rr < 2; rr++)
#pragma unroll
        for (int cc = 0; cc < 4; cc++) pa[rr][cc] += qv[rr] * kv[cc];
    }
#pragma unroll
    for (int rr = 0; rr < 2; rr++)
#pragma unroll
      for (int cc = 0; cc < 4; cc++) {
        int r = 2 * rb + rr, i = 2 * r + 1, j = 4 * jb + cc;
        PmT[j][r] = (j <= i) ? expf(cuml[i] - cuml[j]) * pa[rr][cc] : 0.f;
      }
  }
  __syncthreads();
  for (int e = tid; e < 4096; e += 256) {
    int d = e >> 6, m = e & 63;
    kTc[m][d] = bf2f(S0Tbuf[base * 4096 + e]);
  }
  __syncthreads();
  float o[2][4];
  {
    float a1[2][4] = {}, a2[2][4] = {};
#pragma unroll 4
    for (int m = 0; m < 64; m++) {
      f32x2 qv = *(const f32x2*)&qT[m][2 * rb];
      f32x4 sv = *(const f32x4*)&kTc[m][4 * jb];
#pragma unroll
      for (int rr = 0; rr < 2; rr++)
#pragma unroll
        for (int cc = 0; cc < 4; cc++) a1[rr][cc] += qv[rr] * sv[cc];
    }
    // triangular: PmT[j][r]=0 for j>2r+1; max needed j = 4rb+3
#pragma unroll 4
    for (int j = 0; j < 4 * rb + 4; j++) {
      f32x2 pv = *(const f32x2*)&PmT[j][2 * rb];
      f32x4 uv = *(const f32x4*)&Ul[j][4 * jb];
#pragma unroll
      for (int rr = 0; rr < 2; rr++)
#pragma unroll
        for (int cc = 0; cc < 4; cc++) a2[rr][cc] += pv[rr] * uv[cc];
    }
#pragma unroll
    for (int rr = 0; rr < 2; rr++) {
      float ec = expf(cuml[2 * (2 * rb + rr) + 1]);
#pragma unroll
      for (int cc = 0; cc < 4; cc++) o[rr][cc] = a1[rr][cc] * ec + a2[rr][cc];
    }
  }
  __syncthreads();
  float* ol = &qT[0][0];   // [32][68]
#pragma unroll
  for (int rr = 0; rr < 2; rr++)
#pragma unroll
    for (int cc = 0; cc < 4; cc++)
      ol[(2 * rb + rr) * 68 + 4 * jb + cc] = o[rr][cc];
  __syncthreads();
  for (int e = tid; e < 2048; e += 256) {
    int r = e >> 6, d = e & 63;
    float ov = ol[r * 68 + d];
    float ss = ov * ov;
#pragma unroll
    for (int off = 32; off; off >>= 1) ss += __shfl_xor(ss, off);
    float on = ov * rsqrtf(ss * (1.f / 64.f) + 1e-5f) * nwl[d];
    int t = c * 32 + r;
    float gt = P[(size_t)t * NP + 5168 + h * 64 + d];
    float sw = gt / (1.f + expf(-gt));
    ybuf[(size_t)t * 1024 + h * 64 + d] = f2bf(on * sw);
  }
}

extern "C" void kernel_launch(void* const* d_in, const int* in_sizes, int n_in,
                              void* d_out, int out_size, void* d_ws, size_t ws_size,
                              hipStream_t stream) {
  const float* x       = (const float*)d_in[0];
  const float* Wq      = (const float*)d_in[1];
  const float* Wk      = (const float*)d_in[2];
  const float* Wv      = (const float*)d_in[3];
  const float* Wb      = (const float*)d_in[4];
  const float* Wa      = (const float*)d_in[5];
  const float* A_log   = (const float*)d_in[6];
  const float* dt_bias = (const float*)d_in[7];
  const float* Wg      = (const float*)d_in[8];
  const float* nw      = (const float*)d_in[9];
  const float* Wo      = (const float*)d_in[10];
  float* out = (float*)d_out;

  char* w = (char*)d_ws;
  size_t used = 0;
  auto alloc = [&](size_t bytes) {
    char* p = w + used; used += (bytes + 255) & ~(size_t)255; return p;
  };
  u16*   xb    = (u16*)  alloc(2048UL * 1024 * 2);
  u16*   WT    = (u16*)  alloc(6272UL * 1024 * 2);   // padded to 49*128 rows
  u16*   WoT   = (u16*)  alloc(1024UL * 1024 * 2);
  float* P     = (float*)alloc(2048UL * NP * 4);
  float* betab = (float*)alloc(4096UL * 16 * 4);
  float* gbuf  = (float*)alloc(2048UL * 16 * 4);
  u16*   ybuf  = (u16*)  alloc(2048UL * 1024 * 2);
  u16*   Wbuf  = (u16*)  alloc((size_t)NC * 16 * 4096 * 2);
  u16*   Uvbuf = (u16*)  alloc((size_t)NC * 16 * 4096 * 2);
  u16*   S0Tb  = (u16*)  alloc((size_t)NC * 16 * 4096 * 2);
  float* Mbuf  = (float*)alloc((size_t)NC * 16 * 4096 * 4);
  float* NTbuf = (float*)alloc((size_t)NC * 16 * 4096 * 4);
  float* cumb  = (float*)alloc((size_t)NC * 16 * 64 * 4);

  auto tgrid = [](long n) { return dim3((unsigned)((n + 255) / 256)); };
  if (used > ws_size) {
    beacon_kernel<<<tgrid(out_size), 256, 0, stream>>>(out, out_size);
    return;
  }

  // zero pad rows 6192..6271 (edge tile of the 128-wide gemm reads them)
  hipMemsetAsync(WT + 6192UL * 1024, 0, 80UL * 1024 * 2, stream);

  cvt_kernel<<<tgrid(2048L*1024), 256, 0, stream>>>(x, xb, 2048L * 1024);
  transAll_kernel<<<dim3(226, 32), 256, 0, stream>>>(Wq, Wk, Wv, Wb, Wa, Wg, Wo, WT, WoT);

  // P (fp32) = xb @ [Wq|Wk|Wv|Wb|Wa|Wg]
  gemm128<<<dim3(16, 49), 256, 0, stream>>>(xb, WT, P, nullptr, 1024, 1024, NP, NP, 0);
  prep_kernel<<<dim3(2048 * 16), 64, 0, stream>>>(P, A_log, dt_bias, betab, gbuf);

  phaseA_kernel<<<dim3(NC, 16), 256, 0, stream>>>(P, betab, gbuf, Wbuf, Uvbuf, Mbuf, NTbuf, cumb);
  phaseB_kernel<<<dim3(32, 16), 64, 0, stream>>>(Mbuf, NTbuf, S0Tb);
  phaseB2_kernel<<<dim3(NC, 16), 256, 0, stream>>>(Wbuf, S0Tb, Uvbuf);
  phaseC_kernel<<<dim3(NC, 16), 256, 0, stream>>>(P, cumb, Uvbuf, S0Tb, nw, ybuf);

  // out (fp32) = ybuf @ Wo
  gemm128<<<dim3(16, 8), 256, 0, stream>>>(ybuf, WoT, out, nullptr, 1024, 1024, 1024, 1024, 0);
}